// Round 8
// baseline (637.809 us; speedup 1.0000x reference)
//
#include <hip/hip_runtime.h>

// ---------------------------------------------------------------------------
// RefinedQuantumEntanglementLayer on MI355X (gfx950)
//
// out = (l2norm(x) @ expm(Mr-Mr^T) @ expm(Mi-Mi^T) + bias)^2 * softmax(qg)
//
// r8: fused persistent chain (r6/r7) with HIERARCHICAL grid barrier.
// r7 counters: MfmaUtil 2.66% x 486us = 12.9us of real MFMA work (= 32
// GFLOP at peak) -- ~473us was stall, ~47us/barrier. 512 serialized
// far-atomic RMWs on ONE cacheline at ~90ns = 46us -> arrival contention
// is the cost. Now: 32 group counters (separate 128B lines, 16 blocks
// each, parallel) -> 1 top counter (32 RMWs) -> release gen. Monotonic
// round targets (no resets, no reset race). Spin: relaxed polls + one
// __threadfence acquire after exit (r7-verified protocol).
//
// Chain math (deg-8 Paterson-Stockmeyer, s=3, verified r6/r7 absmax
// 4.17e-7; barrier change alters no arithmetic -> absmax must match):
//   X2 = -f(X,X); X3 = -f(X2,X); X4 = f(X2,X2)        [f(A,B) = A*B^T]
//   q0 = I+X+X2/2+X3/6 (f32); q1t = elementwise-transposed q1 (odd flips)
//   E  = f(X4,q1t)+q0 [dual-write -> Et]
//   squarings E' = f(E,Et) [dual -> E't]; W = U^T = f(E3t_B, E3_A)
// main: out = f(Xn,W), epilogue (.+bias)^2*gate (r5 256^2 kernel).
// ---------------------------------------------------------------------------

typedef unsigned int u32;
typedef unsigned short u16;
typedef __attribute__((ext_vector_type(8))) short short8;   // 8 x bf16 raw
typedef __attribute__((ext_vector_type(4))) float f32x4;

#define GLOBAL_AS __attribute__((address_space(1)))
#define LDS_AS    __attribute__((address_space(3)))

constexpr int D = 1024;
constexpr float EXPM_SCALE = 1.0f / 8.0f;   // s = 3 squarings

__device__ __forceinline__ u16 f2bf(float f) {
  union { float f; u32 u; } v; v.f = f;
  u32 r = (v.u + 0x7FFFu + ((v.u >> 16) & 1u)) >> 16;
  return (u16)r;
}
__device__ __forceinline__ float bf2f(u16 u) {
  union { u32 u; float f; } v; v.u = ((u32)u) << 16;
  return v.f;
}

// async global->LDS, 16B per lane; lds base must be wave-uniform.
__device__ __forceinline__ void g2l16(const void* g, void* l) {
  __builtin_amdgcn_global_load_lds((const GLOBAL_AS u32*)g, (LDS_AS u32*)l,
                                   16, 0, 0);
}

// ---------------------------------------------------------------------------
// normalize rows of x -> bf16
__global__ __launch_bounds__(256) void normalize_kernel(
    const float* __restrict__ x, u16* __restrict__ Xn) {
  const int r = blockIdx.x;
  const int t = threadIdx.x;
  const float4 v = ((const float4*)(x + (size_t)r * D))[t];
  float ss = v.x * v.x + v.y * v.y + v.z * v.z + v.w * v.w;
  for (int o = 32; o; o >>= 1) ss += __shfl_down(ss, o);
  __shared__ float s4[4];
  if ((t & 63) == 0) s4[t >> 6] = ss;
  __syncthreads();
  const float tot = s4[0] + s4[1] + s4[2] + s4[3];
  const float inv = rsqrtf(fmaxf(tot, 1e-12f));
  ushort4 o4;
  o4.x = f2bf(v.x * inv); o4.y = f2bf(v.y * inv);
  o4.z = f2bf(v.z * inv); o4.w = f2bf(v.w * inv);
  ((ushort4*)(Xn + (size_t)r * D))[t] = o4;
}

// ---------------------------------------------------------------------------
// fused chain kernel
struct CJob {
  const u16 *A, *B;
  const float* C;
  u16 *Dst, *DT;
  float alpha;
};
struct ChainParams {
  const float *Mr, *Mi, *qg;
  float* gate_out;
  u16 *X0, *X1;
  const u16 *bqX[2], *bqX2[2], *bqX3[2], *bqX4[2];
  float* bq_q0[2];
  u16* bq_q1t[2];
  CJob rounds[7][4];
  int nunits[7];
  u32* bar;  // [32 group lines x 32 u32][top line][gen line], memset 8KB
};

// Hierarchical monotonic grid barrier for 512 blocks, round index k.
// Arrival: fetch_add on grp line (16 blocks/line, 32 lines in parallel);
// 16th of round k bumps top; 32nd top-arrival of round k releases gen=k+1.
// Monotonic targets -> no counter resets -> no reset race. Spin: RELAXED
// polls (no per-poll L2 invalidate); ONE __threadfence acquire after exit.
// Spin capped so a logic failure is loud (absmax), not a hang.
__device__ __forceinline__ void gsync(u32* bar, u32 k, int bid) {
  __syncthreads();
  if (threadIdx.x == 0) {
    u32* grp = bar + ((bid >> 4) << 5);  // 32 u32 = 128B per group line
    u32* top = bar + 1024;
    u32* gen = bar + 1056;
    const u32 a = __hip_atomic_fetch_add(grp, 1u, __ATOMIC_ACQ_REL,
                                         __HIP_MEMORY_SCOPE_AGENT);
    if (a == k * 16u + 15u) {
      const u32 b = __hip_atomic_fetch_add(top, 1u, __ATOMIC_ACQ_REL,
                                           __HIP_MEMORY_SCOPE_AGENT);
      if (b == k * 32u + 31u)
        __hip_atomic_store(gen, k + 1u, __ATOMIC_RELEASE,
                           __HIP_MEMORY_SCOPE_AGENT);
    }
    for (u32 it = 0; it < 3000000u; ++it) {
      if (__hip_atomic_load(gen, __ATOMIC_RELAXED,
                            __HIP_MEMORY_SCOPE_AGENT) > k)
        break;
      __builtin_amdgcn_s_sleep(16);
    }
  }
  __syncthreads();
  __threadfence();  // acquire side: one-time invalidate per block per phase
}

// X = (M - M^T) * EXPM_SCALE -> bf16 (one 64x64 tile)
__device__ void skew_tile(const float* M, u16* X, int bi, int bj, int tid,
                          char* smem) {
  float(*t2)[67] = (float(*)[67])smem;
  const int r0 = tid >> 4, c0 = (tid & 15) * 4;
  float4 own[4];
#pragma unroll
  for (int i = 0; i < 4; ++i) {
    const int r = i * 16 + r0;
    own[i] = *(const float4*)(M + (size_t)(bi * 64 + r) * D + bj * 64 + c0);
    const float4 tr =
        *(const float4*)(M + (size_t)(bj * 64 + r) * D + bi * 64 + c0);
    t2[r][c0 + 0] = tr.x; t2[r][c0 + 1] = tr.y;
    t2[r][c0 + 2] = tr.z; t2[r][c0 + 3] = tr.w;
  }
  __syncthreads();
#pragma unroll
  for (int i = 0; i < 4; ++i) {
    const int r = i * 16 + r0;
    const float o[4] = {own[i].x, own[i].y, own[i].z, own[i].w};
    ushort4 hv;
    u16* hp = (u16*)&hv;
#pragma unroll
    for (int j = 0; j < 4; ++j)
      hp[j] = f2bf((o[j] - t2[c0 + j][r]) * EXPM_SCALE);
    *(ushort4*)(X + (size_t)(bi * 64 + r) * D + bj * 64 + c0) = hv;
  }
}

// one 64x64 GEMM tile: Dst = alpha*(A*B^T) [+C], optional dual write DT.
// r3-proven body: BK=64, 4 waves (2x2, 32x32), dbuf 1-ahead prefetch.
__device__ void gemm_tile(const CJob jb, int bi, int bj, int tid, u16* ldsA,
                          u16* ldsB) {
  const int w = tid >> 6, lane = tid & 63;
  const int wr = w >> 1, wc = w & 1;
  f32x4 acc[2][2];
#pragma unroll
  for (int m = 0; m < 2; ++m)
#pragma unroll
    for (int n = 0; n < 2; ++n) acc[m][n] = f32x4{0.f, 0.f, 0.f, 0.f};
  const int r_l = lane >> 3, c_l = lane & 7;

  auto stage = [&](int buf, int kt) {
    const int k0 = kt * 64;
#pragma unroll
    for (int p = 0; p < 2; ++p) {
      const int row = p * 32 + w * 8 + r_l;
      const int chunk = c_l ^ (row & 7);  // inverse swizzle on global source
      g2l16(jb.A + (size_t)(bi * 64 + row) * D + k0 + chunk * 8,
            (char*)ldsA + buf * 8192 + p * 4096 + w * 1024);
      g2l16(jb.B + (size_t)(bj * 64 + row) * D + k0 + chunk * 8,
            (char*)ldsB + buf * 8192 + p * 4096 + w * 1024);
    }
  };

  stage(0, 0);
  __syncthreads();
  int buf = 0;
  for (int kt = 0; kt < 16; ++kt) {
    if (kt < 15) stage(buf ^ 1, kt + 1);  // prefetch flies under MFMAs
#pragma unroll
    for (int h = 0; h < 2; ++h) {
      const int kk = h * 32 + (lane >> 4) * 8;
      short8 a[2], b[2];
#pragma unroll
      for (int m = 0; m < 2; ++m) {
        const int row = wr * 32 + m * 16 + (lane & 15);
        const int off = row * 128 + ((kk * 2) ^ ((row & 7) << 4));
        a[m] = *(const short8*)((const char*)ldsA + buf * 8192 + off);
      }
#pragma unroll
      for (int n = 0; n < 2; ++n) {
        const int row = wc * 32 + n * 16 + (lane & 15);
        const int off = row * 128 + ((kk * 2) ^ ((row & 7) << 4));
        b[n] = *(const short8*)((const char*)ldsB + buf * 8192 + off);
      }
#pragma unroll
      for (int m = 0; m < 2; ++m)
#pragma unroll
        for (int n = 0; n < 2; ++n)
          acc[m][n] = __builtin_amdgcn_mfma_f32_16x16x32_bf16(
              a[m], b[n], acc[m][n], 0, 0, 0);
    }
    __syncthreads();
    buf ^= 1;
  }
  const int or0 = bi * 64 + wr * 32, oc0 = bj * 64 + wc * 32;
#pragma unroll
  for (int m = 0; m < 2; ++m)
#pragma unroll
    for (int n = 0; n < 2; ++n) {
      const int row0 = or0 + m * 16 + (lane >> 4) * 4;
      const int col = oc0 + n * 16 + (lane & 15);
      ushort4 dv;
      u16* dp = (u16*)&dv;
#pragma unroll
      for (int r = 0; r < 4; ++r) {
        float v = acc[m][n][r] * jb.alpha;
        if (jb.C) v += jb.C[(size_t)(row0 + r) * D + col];
        dp[r] = f2bf(v);
        jb.Dst[(size_t)(row0 + r) * D + col] = dp[r];
      }
      if (jb.DT)  // transposed tile: DT[col][row0..row0+3], one 8B store
        *(ushort4*)(jb.DT + (size_t)col * D + row0) = dv;
    }
}

// elementwise: q0 = I+X+X2/2+X3/6 (f32); q1t = I/24 - X/120 + X2/720
//              - X3/5040 + X4/40320 (bf16)   [8 elems/thread/matrix]
__device__ void buildq_body(const ChainParams& p, int bid, int tid) {
  const int gtid = bid * 256 + tid;
  const size_t idx0 = (size_t)gtid * 8;
  const int i = (int)(idx0 >> 10), j0 = (int)(idx0 & 1023);
#pragma unroll
  for (int m = 0; m < 2; ++m) {
    const short8 xv = *(const short8*)(p.bqX[m] + idx0);
    const short8 x2v = *(const short8*)(p.bqX2[m] + idx0);
    const short8 x3v = *(const short8*)(p.bqX3[m] + idx0);
    const short8 x4v = *(const short8*)(p.bqX4[m] + idx0);
    float q0o[8];
    short8 q1o;
#pragma unroll
    for (int k = 0; k < 8; ++k) {
      const float d = (i == (j0 + k)) ? 1.f : 0.f;
      const float x = bf2f((u16)xv[k]);
      const float x2 = bf2f((u16)x2v[k]);
      const float x3 = bf2f((u16)x3v[k]);
      const float x4 = bf2f((u16)x4v[k]);
      q0o[k] = d + x + x2 * 0.5f + x3 * (1.f / 6.f);
      q1o[k] = (short)f2bf(d * (1.f / 24.f) - x * (1.f / 120.f) +
                           x2 * (1.f / 720.f) - x3 * (1.f / 5040.f) +
                           x4 * (1.f / 40320.f));
    }
#pragma unroll
    for (int k = 0; k < 8; ++k) p.bq_q0[m][idx0 + k] = q0o[k];
    *(short8*)(p.bq_q1t[m] + idx0) = q1o;
  }
}

// softmax of qg (block 0 only, 256 threads x 4 elems)
__device__ void gate_body(const float* qg, float* gout, int tid, char* smem) {
  float* red = (float*)smem;
  const float4 v = ((const float4*)qg)[tid];
  float mx = fmaxf(fmaxf(v.x, v.y), fmaxf(v.z, v.w));
#pragma unroll
  for (int o = 32; o; o >>= 1) mx = fmaxf(mx, __shfl_xor(mx, o));
  if ((tid & 63) == 0) red[tid >> 6] = mx;
  __syncthreads();
  const float M = fmaxf(fmaxf(red[0], red[1]), fmaxf(red[2], red[3]));
  __syncthreads();
  const float e0 = __expf(v.x - M), e1 = __expf(v.y - M),
              e2 = __expf(v.z - M), e3 = __expf(v.w - M);
  float s = e0 + e1 + e2 + e3;
#pragma unroll
  for (int o = 32; o; o >>= 1) s += __shfl_xor(s, o);
  if ((tid & 63) == 0) red[tid >> 6] = s;
  __syncthreads();
  const float S = red[0] + red[1] + red[2] + red[3];
  const float4 o4 = {e0 / S, e1 / S, e2 / S, e3 / S};
  ((float4*)gout)[tid] = o4;
}

__global__ __launch_bounds__(256, 2) void chain_fused(ChainParams p) {
  __shared__ __align__(16) char smem[32768];
  u16* ldsA = (u16*)smem;            // [2][4096] u16
  u16* ldsB = (u16*)(smem + 16384);  // [2][4096] u16
  const int bid = blockIdx.x, tid = threadIdx.x;
  u32 bk = 0;  // barrier round index (identical sequence on all blocks)

  // P0: skew (512 jobs: mat x 16 x 16)
  {
    const int z = bid >> 8, t = bid & 255;
    skew_tile(z ? p.Mi : p.Mr, z ? p.X1 : p.X0, t >> 4, t & 15, tid, smem);
  }
  gsync(p.bar, bk++, bid);

  // 7 GEMM rounds; buildq(+gate) interleaved after round 1
  for (int r = 0; r < 7; ++r) {
    const int njobs = p.nunits[r] << 8;
    for (int j = bid; j < njobs; j += 512) {
      gemm_tile(p.rounds[r][j >> 8], (j >> 4) & 15, j & 15, tid, ldsA, ldsB);
    }
    if (r < 6) gsync(p.bar, bk++, bid);
    if (r == 1) {
      buildq_body(p, bid, tid);
      if (bid == 0) gate_body(p.qg, p.gate_out, tid, smem);
      gsync(p.bar, bk++, bid);
    }
  }
}

// ---------------------------------------------------------------------------
// main GEMM (r5, unchanged): out[r][c] = (f(Xn,W) + bias[c])^2 * gate[c]
// 256x256 tile, BK=64, 8 waves (2x4), 128 KiB dbuf LDS, 1-ahead prefetch.
__global__ __launch_bounds__(512, 1) void main_gemm_kernel(
    const u16* __restrict__ Xn, const u16* __restrict__ Wm,
    const float* __restrict__ bias, const float* __restrict__ gate,
    float* __restrict__ out) {
  const int tid = threadIdx.x;
  const int wid = tid >> 6, lane = tid & 63;
  const int wr = wid >> 2, wc = wid & 3;   // 2 x 4 waves
  __shared__ u16 ldsA[2][256 * 64];
  __shared__ u16 ldsB[2][256 * 64];
  f32x4 acc[8][4];
#pragma unroll
  for (int m = 0; m < 8; ++m)
#pragma unroll
    for (int n = 0; n < 4; ++n) acc[m][n] = f32x4{0.f, 0.f, 0.f, 0.f};

  const int bi = blockIdx.x, bj = blockIdx.y;   // 128 x 4
  const int r8 = tid >> 3;
  const int c_l = tid & 7;

  auto stage = [&](int buf, int kt) {
    const int k0 = kt * 64;
#pragma unroll
    for (int p = 0; p < 4; ++p) {
      const int row = p * 64 + r8;
      const int chunk = c_l ^ (row & 7);
      g2l16(Xn + (size_t)(bi * 256 + row) * D + k0 + chunk * 8,
            (u16*)((char*)&ldsA[buf][0] + p * 8192 + wid * 1024));
      g2l16(Wm + (size_t)(bj * 256 + row) * D + k0 + chunk * 8,
            (u16*)((char*)&ldsB[buf][0] + p * 8192 + wid * 1024));
    }
  };

  stage(0, 0);
  __syncthreads();
  int buf = 0;
  for (int kt = 0; kt < 16; ++kt) {
    if (kt < 15) stage(buf ^ 1, kt + 1);
#pragma unroll
    for (int ks = 0; ks < 2; ++ks) {
      const int kk = ks * 32 + (lane >> 4) * 8;
      short8 a[8], b[4];
#pragma unroll
      for (int m = 0; m < 8; ++m) {
        const int row = wr * 128 + m * 16 + (lane & 15);
        const int off = row * 128 + ((kk * 2) ^ ((row & 7) << 4));
        a[m] = *(const short8*)((const char*)&ldsA[buf][0] + off);
      }
#pragma unroll
      for (int n = 0; n < 4; ++n) {
        const int row = wc * 64 + n * 16 + (lane & 15);
        const int off = row * 128 + ((kk * 2) ^ ((row & 7) << 4));
        b[n] = *(const short8*)((const char*)&ldsB[buf][0] + off);
      }
      __builtin_amdgcn_s_setprio(1);
#pragma unroll
      for (int m = 0; m < 8; ++m)
#pragma unroll
        for (int n = 0; n < 4; ++n)
          acc[m][n] = __builtin_amdgcn_mfma_f32_16x16x32_bf16(
              a[m], b[n], acc[m][n], 0, 0, 0);
      __builtin_amdgcn_s_setprio(0);
    }
    __syncthreads();
    buf ^= 1;
  }
  const int or0 = bi * 256 + wr * 128, oc0 = bj * 256 + wc * 64;
#pragma unroll
  for (int m = 0; m < 8; ++m)
#pragma unroll
    for (int n = 0; n < 4; ++n) {
      const int col = oc0 + n * 16 + (lane & 15);
      const float bc = bias[col], gc = gate[col];
#pragma unroll
      for (int r = 0; r < 4; ++r) {
        const int row = or0 + m * 16 + (lane >> 4) * 4 + r;
        const float t = acc[m][n][r] + bc;
        out[(size_t)row * D + col] = t * t * gc;
      }
    }
}

// ---------------------------------------------------------------------------
extern "C" void kernel_launch(void* const* d_in, const int* in_sizes, int n_in,
                              void* d_out, int out_size, void* d_ws,
                              size_t ws_size, hipStream_t stream) {
  (void)in_sizes; (void)n_in; (void)out_size; (void)ws_size;
  const float* inp = (const float*)d_in[0];
  const float* Mr = (const float*)d_in[1];
  const float* Mi = (const float*)d_in[2];
  const float* bias = (const float*)d_in[3];
  const float* qg = (const float*)d_in[4];
  float* out = (float*)d_out;
  float* gate_out = out + (size_t)32768 * 1024;

  char* ws = (char*)d_ws;
  u16* Xn = (u16*)ws;  // 64 MB
  // per-matrix region (16 MB): 6 bf16 slots (2 MB) + q0 (4 MB f32).
  // lifetimes: s0 X->E3, s1 X2->Et->E3t, s2 X3->E1, s3 X4->E2,
  //            s4 q1t->E1t, s5 E2t
  auto slot = [&](int m, int s) -> u16* {
    return (u16*)(ws + 67108864 + (size_t)m * 16777216 + (size_t)s * 2097152);
  };
  auto q0p = [&](int m) -> float* {
    return (float*)(ws + 67108864 + (size_t)m * 16777216 + 12582912);
  };
  u16* W = (u16*)(ws + 100663296);          // 96 MB: 2 MB
  u32* bar = (u32*)(ws + 104857600);        // 100 MB: barrier state (8 KB)

  hipMemsetAsync(bar, 0, 8192, stream);
  normalize_kernel<<<32768, 256, 0, stream>>>(inp, Xn);

  ChainParams cp{};
  cp.Mr = Mr; cp.Mi = Mi; cp.qg = qg; cp.gate_out = gate_out;
  cp.X0 = slot(0, 0); cp.X1 = slot(1, 0);
  for (int m = 0; m < 2; ++m) {
    cp.bqX[m] = slot(m, 0); cp.bqX2[m] = slot(m, 1);
    cp.bqX3[m] = slot(m, 2); cp.bqX4[m] = slot(m, 3);
    cp.bq_q0[m] = q0p(m); cp.bq_q1t[m] = slot(m, 4);
  }
  // r0 C1: X2 = -f(X,X) -> s1
  for (int m = 0; m < 2; ++m)
    cp.rounds[0][m] = CJob{slot(m, 0), slot(m, 0), nullptr, slot(m, 1),
                           nullptr, -1.f};
  cp.nunits[0] = 2;
  // r1 C2: X3 = -f(X2,X) -> s2 ; X4 = f(X2,X2) -> s3
  for (int m = 0; m < 2; ++m) {
    cp.rounds[1][m * 2 + 0] = CJob{slot(m, 1), slot(m, 0), nullptr, slot(m, 2),
                                   nullptr, -1.f};
    cp.rounds[1][m * 2 + 1] = CJob{slot(m, 1), slot(m, 1), nullptr, slot(m, 3),
                                   nullptr, 1.f};
  }
  cp.nunits[1] = 4;
  // [buildq + gate after r1]
  // r2 E = f(X4, q1t) + q0 -> s0, dual Et -> s1
  for (int m = 0; m < 2; ++m)
    cp.rounds[2][m] = CJob{slot(m, 3), slot(m, 4), q0p(m), slot(m, 0),
                           slot(m, 1), 1.f};
  cp.nunits[2] = 2;
  // r3 sq1: E1 = f(E,Et) -> s2, dual E1t -> s4
  for (int m = 0; m < 2; ++m)
    cp.rounds[3][m] = CJob{slot(m, 0), slot(m, 1), nullptr, slot(m, 2),
                           slot(m, 4), 1.f};
  cp.nunits[3] = 2;
  // r4 sq2: E2 = f(E1,E1t) -> s3, dual E2t -> s5
  for (int m = 0; m < 2; ++m)
    cp.rounds[4][m] = CJob{slot(m, 2), slot(m, 4), nullptr, slot(m, 3),
                           slot(m, 5), 1.f};
  cp.nunits[4] = 2;
  // r5 sq3: E3 = f(E2,E2t) -> s0, dual E3t -> s1
  for (int m = 0; m < 2; ++m)
    cp.rounds[5][m] = CJob{slot(m, 3), slot(m, 5), nullptr, slot(m, 0),
                           slot(m, 1), 1.f};
  cp.nunits[5] = 2;
  // r6 W = U^T = f(E3t_B, E3_A)
  cp.rounds[6][0] = CJob{slot(1, 1), slot(0, 0), nullptr, W, nullptr, 1.f};
  cp.nunits[6] = 1;
  cp.bar = bar;

  chain_fused<<<512, 256, 0, stream>>>(cp);

  main_gemm_kernel<<<dim3(128, 4), 512, 0, stream>>>(Xn, W, bias, gate_out,
                                                     out);
}

// Round 9
// 243.819 us; speedup vs baseline: 2.6159x; 2.6159x over previous
//
#include <hip/hip_runtime.h>

// ---------------------------------------------------------------------------
// RefinedQuantumEntanglementLayer on MI355X (gfx950)
//
// out = (l2norm(x) @ expm(Mr-Mr^T) @ expm(Mi-Mi^T) + bias)^2 * softmax(qg)
//
// r9: REVERT to multi-kernel chain (r5 structure) with the deg-8 math
// verified in r6-r8 (absmax 4.17e-7). The persistent-grid fused chain was
// abandoned: 3 rounds of barrier fixes (relaxed polls r7, hierarchical
// arrival r8) all landed ~490-530us vs ~120us multi-kernel -- software
// grid barriers at 512 blocks pay a per-block L2 invalidate + far-atomic
// round trip per phase that the hardware kernel boundary does once,
// globally, overlapped with dispatch. Fusion loses when phases are ~5us.
//
// New this round: the normalize kernel (35us standalone) is FOLDED into
// the 9 chain launches as a per-launch block tail -- chain rounds leave
// the GPU ~3/4 idle (512 gemm blocks, latency-bound), so ~3641 normalize
// rows per launch stream under them using idle bandwidth.
//
// Chain math (deg-8 Paterson-Stockmeyer, s=3):  [f(A,B) = A*B^T]
//   X2 = -f(X,X); X3 = -f(X2,X); X4 = f(X2,X2)
//   q0 = I+X+X2/2+X3/6 (f32); q1t = elementwise-transposed q1 (odd flips)
//   E  = f(X4,q1t)+q0 [dual-write -> Et]
//   squarings E' = f(E,Et) [dual -> E't]; W = U^T = f(E3t_B, E3_A)
// main: out = f(Xn,W), epilogue (.+bias)^2*gate (r5 256^2 kernel, 90us).
// ---------------------------------------------------------------------------

typedef unsigned int u32;
typedef unsigned short u16;
typedef __attribute__((ext_vector_type(8))) short short8;   // 8 x bf16 raw
typedef __attribute__((ext_vector_type(4))) float f32x4;

#define GLOBAL_AS __attribute__((address_space(1)))
#define LDS_AS    __attribute__((address_space(3)))

constexpr int D = 1024;
constexpr float EXPM_SCALE = 1.0f / 8.0f;   // s = 3 squarings

__device__ __forceinline__ u16 f2bf(float f) {
  union { float f; u32 u; } v; v.f = f;
  u32 r = (v.u + 0x7FFFu + ((v.u >> 16) & 1u)) >> 16;
  return (u16)r;
}
__device__ __forceinline__ float bf2f(u16 u) {
  union { u32 u; float f; } v; v.u = ((u32)u) << 16;
  return v.f;
}

// async global->LDS, 16B per lane; lds base must be wave-uniform.
__device__ __forceinline__ void g2l16(const void* g, void* l) {
  __builtin_amdgcn_global_load_lds((const GLOBAL_AS u32*)g, (LDS_AS u32*)l,
                                   16, 0, 0);
}

// ---------------------------------------------------------------------------
// normalize one row of x -> bf16 (shared tail body for chain launches)
__device__ void norm_row(const float* __restrict__ x, u16* __restrict__ Xn,
                         int r, int tid, float* s4) {
  const float4 v = ((const float4*)(x + (size_t)r * D))[tid];
  float ss = v.x * v.x + v.y * v.y + v.z * v.z + v.w * v.w;
  for (int o = 32; o; o >>= 1) ss += __shfl_down(ss, o);
  if ((tid & 63) == 0) s4[tid >> 6] = ss;
  __syncthreads();
  const float tot = s4[0] + s4[1] + s4[2] + s4[3];
  const float inv = rsqrtf(fmaxf(tot, 1e-12f));
  ushort4 o4;
  o4.x = f2bf(v.x * inv); o4.y = f2bf(v.y * inv);
  o4.z = f2bf(v.z * inv); o4.w = f2bf(v.w * inv);
  ((ushort4*)(Xn + (size_t)r * D))[tid] = o4;
}

// ---------------------------------------------------------------------------
// launch 1: skew tiles (512 jobs) + normalize tail
struct SkewParams {
  const float *Mr, *Mi;
  u16 *X0, *X1;
  const float* x;
  u16* Xn;
  int row0;
};
__global__ __launch_bounds__(256) void skew_norm_kernel(SkewParams p) {
  __shared__ __align__(16) float t2[64][67];
  const int bid = blockIdx.x, tid = threadIdx.x;
  if (bid >= 512) {
    norm_row(p.x, p.Xn, p.row0 + bid - 512, tid, &t2[0][0]);
    return;
  }
  const int z = bid >> 8, t = bid & 255;
  const float* M = z ? p.Mi : p.Mr;
  u16* X = z ? p.X1 : p.X0;
  const int bi = t >> 4, bj = t & 15;
  const int r0 = tid >> 4, c0 = (tid & 15) * 4;
  float4 own[4];
#pragma unroll
  for (int i = 0; i < 4; ++i) {
    const int r = i * 16 + r0;
    own[i] = *(const float4*)(M + (size_t)(bi * 64 + r) * D + bj * 64 + c0);
    const float4 tr =
        *(const float4*)(M + (size_t)(bj * 64 + r) * D + bi * 64 + c0);
    t2[r][c0 + 0] = tr.x; t2[r][c0 + 1] = tr.y;
    t2[r][c0 + 2] = tr.z; t2[r][c0 + 3] = tr.w;
  }
  __syncthreads();
#pragma unroll
  for (int i = 0; i < 4; ++i) {
    const int r = i * 16 + r0;
    const float o[4] = {own[i].x, own[i].y, own[i].z, own[i].w};
    ushort4 hv;
    u16* hp = (u16*)&hv;
#pragma unroll
    for (int j = 0; j < 4; ++j)
      hp[j] = f2bf((o[j] - t2[c0 + j][r]) * EXPM_SCALE);
    *(ushort4*)(X + (size_t)(bi * 64 + r) * D + bj * 64 + c0) = hv;
  }
}

// ---------------------------------------------------------------------------
// chain GEMM rounds: tile jobs + normalize tail.
// Tile body is the r3-proven 64x64, BK=64, 4 waves (2x2, 32x32 each),
// dbuf 1-ahead prefetch. Dst = alpha*(A*B^T) [+C], optional dual write DT.
struct CJob {
  const u16 *A, *B;
  const float* C;
  u16 *Dst, *DT;
  float alpha;
};
struct GNParams {
  CJob jobs[4];
  int njobs;  // nunits * 256 tile jobs
  const float* x;
  u16* Xn;
  int row0;
};
__global__ __launch_bounds__(256) void gemm_norm_kernel(GNParams p) {
  __shared__ __align__(16) u16 ldsA[2][64 * 64];
  __shared__ __align__(16) u16 ldsB[2][64 * 64];
  const int bid = blockIdx.x, tid = threadIdx.x;
  if (bid >= p.njobs) {
    norm_row(p.x, p.Xn, p.row0 + bid - p.njobs, tid, (float*)&ldsA[0][0]);
    return;
  }
  const CJob jb = p.jobs[bid >> 8];
  const int bi = (bid >> 4) & 15, bj = bid & 15;
  const int w = tid >> 6, lane = tid & 63;
  const int wr = w >> 1, wc = w & 1;
  f32x4 acc[2][2];
#pragma unroll
  for (int m = 0; m < 2; ++m)
#pragma unroll
    for (int n = 0; n < 2; ++n) acc[m][n] = f32x4{0.f, 0.f, 0.f, 0.f};
  const int r_l = lane >> 3, c_l = lane & 7;

  auto stage = [&](int buf, int kt) {
    const int k0 = kt * 64;
#pragma unroll
    for (int pp = 0; pp < 2; ++pp) {
      const int row = pp * 32 + w * 8 + r_l;
      const int chunk = c_l ^ (row & 7);  // inverse swizzle on global source
      g2l16(jb.A + (size_t)(bi * 64 + row) * D + k0 + chunk * 8,
            (char*)&ldsA[buf][0] + pp * 4096 + w * 1024);
      g2l16(jb.B + (size_t)(bj * 64 + row) * D + k0 + chunk * 8,
            (char*)&ldsB[buf][0] + pp * 4096 + w * 1024);
    }
  };

  stage(0, 0);
  __syncthreads();
  int buf = 0;
  for (int kt = 0; kt < 16; ++kt) {
    if (kt < 15) stage(buf ^ 1, kt + 1);  // prefetch flies under MFMAs
#pragma unroll
    for (int h = 0; h < 2; ++h) {
      const int kk = h * 32 + (lane >> 4) * 8;
      short8 a[2], b[2];
#pragma unroll
      for (int m = 0; m < 2; ++m) {
        const int row = wr * 32 + m * 16 + (lane & 15);
        const int off = row * 128 + ((kk * 2) ^ ((row & 7) << 4));
        a[m] = *(const short8*)((const char*)&ldsA[buf][0] + off);
      }
#pragma unroll
      for (int n = 0; n < 2; ++n) {
        const int row = wc * 32 + n * 16 + (lane & 15);
        const int off = row * 128 + ((kk * 2) ^ ((row & 7) << 4));
        b[n] = *(const short8*)((const char*)&ldsB[buf][0] + off);
      }
#pragma unroll
      for (int m = 0; m < 2; ++m)
#pragma unroll
        for (int n = 0; n < 2; ++n)
          acc[m][n] = __builtin_amdgcn_mfma_f32_16x16x32_bf16(
              a[m], b[n], acc[m][n], 0, 0, 0);
    }
    __syncthreads();
    buf ^= 1;
  }
  const int or0 = bi * 64 + wr * 32, oc0 = bj * 64 + wc * 32;
#pragma unroll
  for (int m = 0; m < 2; ++m)
#pragma unroll
    for (int n = 0; n < 2; ++n) {
      const int row0 = or0 + m * 16 + (lane >> 4) * 4;
      const int col = oc0 + n * 16 + (lane & 15);
      ushort4 dv;
      u16* dp = (u16*)&dv;
#pragma unroll
      for (int r = 0; r < 4; ++r) {
        float v = acc[m][n][r] * jb.alpha;
        if (jb.C) v += jb.C[(size_t)(row0 + r) * D + col];
        dp[r] = f2bf(v);
        jb.Dst[(size_t)(row0 + r) * D + col] = dp[r];
      }
      if (jb.DT)  // transposed tile: DT[col][row0..row0+3], one 8B store
        *(ushort4*)(jb.DT + (size_t)col * D + row0) = dv;
    }
}

// ---------------------------------------------------------------------------
// buildq launch: 512 elementwise blocks + gate block (bid 512) + norm tail.
// q0 = I+X+X2/2+X3/6 (f32); q1t = I/24 - X/120 + X2/720 - X3/5040
//      + X4/40320 (bf16, elementwise-transposed q1)
struct BQParams {
  const u16 *X[2], *X2[2], *X3[2], *X4[2];
  float* q0[2];
  u16* q1t[2];
  const float* qg;
  float* gate_out;
  const float* x;
  u16* Xn;
  int row0;
};
__global__ __launch_bounds__(256) void buildq_norm_kernel(BQParams p) {
  __shared__ __align__(16) float red[16];
  const int bid = blockIdx.x, tid = threadIdx.x;
  if (bid > 512) {
    norm_row(p.x, p.Xn, p.row0 + bid - 513, tid, red);
    return;
  }
  if (bid == 512) {  // gate softmax
    const float4 v = ((const float4*)p.qg)[tid];
    float mx = fmaxf(fmaxf(v.x, v.y), fmaxf(v.z, v.w));
#pragma unroll
    for (int o = 32; o; o >>= 1) mx = fmaxf(mx, __shfl_xor(mx, o));
    if ((tid & 63) == 0) red[tid >> 6] = mx;
    __syncthreads();
    const float M = fmaxf(fmaxf(red[0], red[1]), fmaxf(red[2], red[3]));
    __syncthreads();
    const float e0 = __expf(v.x - M), e1 = __expf(v.y - M),
                e2 = __expf(v.z - M), e3 = __expf(v.w - M);
    float s = e0 + e1 + e2 + e3;
#pragma unroll
    for (int o = 32; o; o >>= 1) s += __shfl_xor(s, o);
    if ((tid & 63) == 0) red[tid >> 6] = s;
    __syncthreads();
    const float S = red[0] + red[1] + red[2] + red[3];
    const float4 o4 = {e0 / S, e1 / S, e2 / S, e3 / S};
    ((float4*)p.gate_out)[tid] = o4;
    return;
  }
  const size_t idx0 = ((size_t)bid * 256 + tid) * 8;
  const int i = (int)(idx0 >> 10), j0 = (int)(idx0 & 1023);
#pragma unroll
  for (int m = 0; m < 2; ++m) {
    const short8 xv = *(const short8*)(p.X[m] + idx0);
    const short8 x2v = *(const short8*)(p.X2[m] + idx0);
    const short8 x3v = *(const short8*)(p.X3[m] + idx0);
    const short8 x4v = *(const short8*)(p.X4[m] + idx0);
    float q0o[8];
    short8 q1o;
#pragma unroll
    for (int k = 0; k < 8; ++k) {
      const float d = (i == (j0 + k)) ? 1.f : 0.f;
      const float x = bf2f((u16)xv[k]);
      const float x2 = bf2f((u16)x2v[k]);
      const float x3 = bf2f((u16)x3v[k]);
      const float x4 = bf2f((u16)x4v[k]);
      q0o[k] = d + x + x2 * 0.5f + x3 * (1.f / 6.f);
      q1o[k] = (short)f2bf(d * (1.f / 24.f) - x * (1.f / 120.f) +
                           x2 * (1.f / 720.f) - x3 * (1.f / 5040.f) +
                           x4 * (1.f / 40320.f));
    }
#pragma unroll
    for (int k = 0; k < 8; ++k) p.q0[m][idx0 + k] = q0o[k];
    *(short8*)(p.q1t[m] + idx0) = q1o;
  }
}

// ---------------------------------------------------------------------------
// main GEMM (r5, unchanged): out[r][c] = (f(Xn,W) + bias[c])^2 * gate[c]
// 256x256 tile, BK=64, 8 waves (2x4), 128 KiB dbuf LDS, 1-ahead prefetch.
__global__ __launch_bounds__(512, 1) void main_gemm_kernel(
    const u16* __restrict__ Xn, const u16* __restrict__ Wm,
    const float* __restrict__ bias, const float* __restrict__ gate,
    float* __restrict__ out) {
  const int tid = threadIdx.x;
  const int wid = tid >> 6, lane = tid & 63;
  const int wr = wid >> 2, wc = wid & 3;   // 2 x 4 waves
  __shared__ u16 ldsA[2][256 * 64];
  __shared__ u16 ldsB[2][256 * 64];
  f32x4 acc[8][4];
#pragma unroll
  for (int m = 0; m < 8; ++m)
#pragma unroll
    for (int n = 0; n < 4; ++n) acc[m][n] = f32x4{0.f, 0.f, 0.f, 0.f};

  const int bi = blockIdx.x, bj = blockIdx.y;   // 128 x 4
  const int r8 = tid >> 3;
  const int c_l = tid & 7;

  auto stage = [&](int buf, int kt) {
    const int k0 = kt * 64;
#pragma unroll
    for (int p = 0; p < 4; ++p) {
      const int row = p * 64 + r8;
      const int chunk = c_l ^ (row & 7);
      g2l16(Xn + (size_t)(bi * 256 + row) * D + k0 + chunk * 8,
            (u16*)((char*)&ldsA[buf][0] + p * 8192 + wid * 1024));
      g2l16(Wm + (size_t)(bj * 256 + row) * D + k0 + chunk * 8,
            (u16*)((char*)&ldsB[buf][0] + p * 8192 + wid * 1024));
    }
  };

  stage(0, 0);
  __syncthreads();
  int buf = 0;
  for (int kt = 0; kt < 16; ++kt) {
    if (kt < 15) stage(buf ^ 1, kt + 1);
#pragma unroll
    for (int ks = 0; ks < 2; ++ks) {
      const int kk = ks * 32 + (lane >> 4) * 8;
      short8 a[8], b[4];
#pragma unroll
      for (int m = 0; m < 8; ++m) {
        const int row = wr * 128 + m * 16 + (lane & 15);
        const int off = row * 128 + ((kk * 2) ^ ((row & 7) << 4));
        a[m] = *(const short8*)((const char*)&ldsA[buf][0] + off);
      }
#pragma unroll
      for (int n = 0; n < 4; ++n) {
        const int row = wc * 64 + n * 16 + (lane & 15);
        const int off = row * 128 + ((kk * 2) ^ ((row & 7) << 4));
        b[n] = *(const short8*)((const char*)&ldsB[buf][0] + off);
      }
      __builtin_amdgcn_s_setprio(1);
#pragma unroll
      for (int m = 0; m < 8; ++m)
#pragma unroll
        for (int n = 0; n < 4; ++n)
          acc[m][n] = __builtin_amdgcn_mfma_f32_16x16x32_bf16(
              a[m], b[n], acc[m][n], 0, 0, 0);
      __builtin_amdgcn_s_setprio(0);
    }
    __syncthreads();
    buf ^= 1;
  }
  const int or0 = bi * 256 + wr * 128, oc0 = bj * 256 + wc * 64;
#pragma unroll
  for (int m = 0; m < 8; ++m)
#pragma unroll
    for (int n = 0; n < 4; ++n) {
      const int col = oc0 + n * 16 + (lane & 15);
      const float bc = bias[col], gc = gate[col];
#pragma unroll
      for (int r = 0; r < 4; ++r) {
        const int row = or0 + m * 16 + (lane >> 4) * 4 + r;
        const float t = acc[m][n][r] + bc;
        out[(size_t)row * D + col] = t * t * gc;
      }
    }
}

// ---------------------------------------------------------------------------
extern "C" void kernel_launch(void* const* d_in, const int* in_sizes, int n_in,
                              void* d_out, int out_size, void* d_ws,
                              size_t ws_size, hipStream_t stream) {
  (void)in_sizes; (void)n_in; (void)out_size; (void)ws_size;
  const float* inp = (const float*)d_in[0];
  const float* Mr = (const float*)d_in[1];
  const float* Mi = (const float*)d_in[2];
  const float* bias = (const float*)d_in[3];
  const float* qg = (const float*)d_in[4];
  float* out = (float*)d_out;
  float* gate_out = out + (size_t)32768 * 1024;

  char* ws = (char*)d_ws;
  u16* Xn = (u16*)ws;  // 64 MB
  // per-matrix region (16 MB): 6 bf16 slots (2 MB) + q0 (4 MB f32).
  // lifetimes: s0 X->E3, s1 X2->Et->E3t, s2 X3->E1, s3 X4->E2,
  //            s4 q1t->E1t, s5 E2t
  auto slot = [&](int m, int s) -> u16* {
    return (u16*)(ws + 67108864 + (size_t)m * 16777216 + (size_t)s * 2097152);
  };
  auto q0p = [&](int m) -> float* {
    return (float*)(ws + 67108864 + (size_t)m * 16777216 + 12582912);
  };
  u16* W = (u16*)(ws + 100663296);  // 96 MB: 2 MB; total ws use ~98 MB

  // normalize rows are spread across the 9 chain launches as block tails
  const int CH = 3641;  // 8*3641 + 3640 = 32768
  int row0 = 0;

  // L1: skew
  {
    SkewParams sp{Mr, Mi, slot(0, 0), slot(1, 0), inp, Xn, row0};
    skew_norm_kernel<<<512 + CH, 256, 0, stream>>>(sp);
    row0 += CH;
  }
  GNParams gp{};
  gp.x = inp; gp.Xn = Xn;
  // L2: X2 = -f(X,X) -> s1
  for (int m = 0; m < 2; ++m)
    gp.jobs[m] = CJob{slot(m, 0), slot(m, 0), nullptr, slot(m, 1), nullptr,
                      -1.f};
  gp.njobs = 512; gp.row0 = row0;
  gemm_norm_kernel<<<512 + CH, 256, 0, stream>>>(gp);
  row0 += CH;
  // L3: X3 = -f(X2,X) -> s2 ; X4 = f(X2,X2) -> s3
  for (int m = 0; m < 2; ++m) {
    gp.jobs[m * 2 + 0] = CJob{slot(m, 1), slot(m, 0), nullptr, slot(m, 2),
                              nullptr, -1.f};
    gp.jobs[m * 2 + 1] = CJob{slot(m, 1), slot(m, 1), nullptr, slot(m, 3),
                              nullptr, 1.f};
  }
  gp.njobs = 1024; gp.row0 = row0;
  gemm_norm_kernel<<<1024 + CH, 256, 0, stream>>>(gp);
  row0 += CH;
  // L4: buildq (q0, q1t) + gate
  {
    BQParams bq{};
    for (int m = 0; m < 2; ++m) {
      bq.X[m] = slot(m, 0); bq.X2[m] = slot(m, 1);
      bq.X3[m] = slot(m, 2); bq.X4[m] = slot(m, 3);
      bq.q0[m] = q0p(m); bq.q1t[m] = slot(m, 4);
    }
    bq.qg = qg; bq.gate_out = gate_out;
    bq.x = inp; bq.Xn = Xn; bq.row0 = row0;
    buildq_norm_kernel<<<513 + CH, 256, 0, stream>>>(bq);
    row0 += CH;
  }
  // L5: E = f(X4, q1t) + q0 -> s0, dual Et -> s1
  for (int m = 0; m < 2; ++m)
    gp.jobs[m] = CJob{slot(m, 3), slot(m, 4), q0p(m), slot(m, 0), slot(m, 1),
                      1.f};
  gp.njobs = 512; gp.row0 = row0;
  gemm_norm_kernel<<<512 + CH, 256, 0, stream>>>(gp);
  row0 += CH;
  // L6: sq1: E1 = f(E,Et) -> s2, dual E1t -> s4
  for (int m = 0; m < 2; ++m)
    gp.jobs[m] = CJob{slot(m, 0), slot(m, 1), nullptr, slot(m, 2), slot(m, 4),
                      1.f};
  gp.row0 = row0;
  gemm_norm_kernel<<<512 + CH, 256, 0, stream>>>(gp);
  row0 += CH;
  // L7: sq2: E2 = f(E1,E1t) -> s3, dual E2t -> s5
  for (int m = 0; m < 2; ++m)
    gp.jobs[m] = CJob{slot(m, 2), slot(m, 4), nullptr, slot(m, 3), slot(m, 5),
                      1.f};
  gp.row0 = row0;
  gemm_norm_kernel<<<512 + CH, 256, 0, stream>>>(gp);
  row0 += CH;
  // L8: sq3: E3 = f(E2,E2t) -> s0, dual E3t -> s1
  for (int m = 0; m < 2; ++m)
    gp.jobs[m] = CJob{slot(m, 3), slot(m, 5), nullptr, slot(m, 0), slot(m, 1),
                      1.f};
  gp.row0 = row0;
  gemm_norm_kernel<<<512 + CH, 256, 0, stream>>>(gp);
  row0 += CH;
  // L9: W = U^T = f(E3t_B, E3_A)
  gp.jobs[0] = CJob{slot(1, 1), slot(0, 0), nullptr, W, nullptr, 1.f};
  gp.njobs = 256; gp.row0 = row0;
  gemm_norm_kernel<<<256 + (32768 - row0), 256, 0, stream>>>(gp);

  main_gemm_kernel<<<dim3(128, 4), 512, 0, stream>>>(Xn, W, bias, gate_out,
                                                     out);
}

// Round 10
// 236.046 us; speedup vs baseline: 2.7021x; 1.0329x over previous
//
#include <hip/hip_runtime.h>

// ---------------------------------------------------------------------------
// RefinedQuantumEntanglementLayer on MI355X (gfx950)
//
// out = (l2norm(x) @ expm(Mr-Mr^T) @ expm(Mi-Mi^T) + bias)^2 * softmax(qg)
//
// r10:
//  * main GEMM: 4-buffer BK=32 pipeline with counted vmcnt (T3/T4).
//    vmcnt(8) BEFORE raw s_barrier (own loads done pre-barrier -> all
//    threads' loads done post-barrier); stage(s+3) issued AFTER barrier
//    (overwrites buf(s-1), provably past all reads). No vmcnt(0) drains
//    in steady state. Banking: 64B rows, chunk ^= (row>>1)&3 -> 2-way
//    (free). K ascends in same 32-chunks -> accumulation bit-identical.
//  * chain: 8 launches (buildq fused into the X3/X4 round: one block
//    computes both X3 and X4 per tile, epilogue rounds through bf16 so
//    q0/q1t values are bit-identical to r9's separate pass).
//  * normalize: 8 rows/block tails (512/launch, CH=4096).
//
// Chain math (deg-8 Paterson-Stockmeyer, s=3):  [f(A,B) = A*B^T]
//   X2 = -f(X,X); X3 = -f(X2,X); X4 = f(X2,X2)
//   q0 = I+X+X2/2+X3/6 (f32); q1t = elementwise-transposed q1 (odd flips)
//   E  = f(X4,q1t)+q0 [dual-write -> Et]
//   squarings E' = f(E,Et) [dual -> E't]; W = U^T = f(E3t_B, E3_A)
// ---------------------------------------------------------------------------

typedef unsigned int u32;
typedef unsigned short u16;
typedef __attribute__((ext_vector_type(8))) short short8;   // 8 x bf16 raw
typedef __attribute__((ext_vector_type(4))) float f32x4;

#define GLOBAL_AS __attribute__((address_space(1)))
#define LDS_AS    __attribute__((address_space(3)))

constexpr int D = 1024;
constexpr float EXPM_SCALE = 1.0f / 8.0f;   // s = 3 squarings

__device__ __forceinline__ u16 f2bf(float f) {
  union { float f; u32 u; } v; v.f = f;
  u32 r = (v.u + 0x7FFFu + ((v.u >> 16) & 1u)) >> 16;
  return (u16)r;
}
__device__ __forceinline__ float bf2f(u16 u) {
  union { u32 u; float f; } v; v.u = ((u32)u) << 16;
  return v.f;
}

// async global->LDS, 16B per lane; lds base must be wave-uniform.
__device__ __forceinline__ void g2l16(const void* g, void* l) {
  __builtin_amdgcn_global_load_lds((const GLOBAL_AS u32*)g, (LDS_AS u32*)l,
                                   16, 0, 0);
}

#define WAITV(N)                                                   \
  do {                                                             \
    asm volatile("s_waitcnt vmcnt(" #N ")" ::: "memory");          \
    __builtin_amdgcn_sched_barrier(0);                             \
  } while (0)

// ---------------------------------------------------------------------------
// normalize 8 rows of x -> bf16 (tail body shared by chain launches)
__device__ void norm_rows8(const float* __restrict__ x, u16* __restrict__ Xn,
                           int r0, int tid, float* sred) {
  float4 v[8];
#pragma unroll
  for (int i = 0; i < 8; ++i)
    v[i] = ((const float4*)(x + (size_t)(r0 + i) * D))[tid];
  float ss[8];
#pragma unroll
  for (int i = 0; i < 8; ++i)
    ss[i] = v[i].x * v[i].x + v[i].y * v[i].y + v[i].z * v[i].z +
            v[i].w * v[i].w;
  for (int o = 32; o; o >>= 1)
#pragma unroll
    for (int i = 0; i < 8; ++i) ss[i] += __shfl_down(ss[i], o);
  const int w = tid >> 6;
  if ((tid & 63) == 0)
#pragma unroll
    for (int i = 0; i < 8; ++i) sred[i * 4 + w] = ss[i];
  __syncthreads();
#pragma unroll
  for (int i = 0; i < 8; ++i) {
    const float tot =
        sred[i * 4 + 0] + sred[i * 4 + 1] + sred[i * 4 + 2] + sred[i * 4 + 3];
    const float inv = rsqrtf(fmaxf(tot, 1e-12f));
    ushort4 o4;
    o4.x = f2bf(v[i].x * inv); o4.y = f2bf(v[i].y * inv);
    o4.z = f2bf(v[i].z * inv); o4.w = f2bf(v[i].w * inv);
    ((ushort4*)(Xn + (size_t)(r0 + i) * D))[tid] = o4;
  }
}

// ---------------------------------------------------------------------------
// L1: skew tiles (512 jobs) + norm tail
struct SkewParams {
  const float *Mr, *Mi;
  u16 *X0, *X1;
  const float* x;
  u16* Xn;
  int row0;
};
__global__ __launch_bounds__(256) void skew_norm_kernel(SkewParams p) {
  __shared__ __align__(16) float t2[64][67];
  const int bid = blockIdx.x, tid = threadIdx.x;
  if (bid >= 512) {
    norm_rows8(p.x, p.Xn, p.row0 + (bid - 512) * 8, tid, &t2[0][0]);
    return;
  }
  const int z = bid >> 8, t = bid & 255;
  const float* M = z ? p.Mi : p.Mr;
  u16* X = z ? p.X1 : p.X0;
  const int bi = t >> 4, bj = t & 15;
  const int r0 = tid >> 4, c0 = (tid & 15) * 4;
  float4 own[4];
#pragma unroll
  for (int i = 0; i < 4; ++i) {
    const int r = i * 16 + r0;
    own[i] = *(const float4*)(M + (size_t)(bi * 64 + r) * D + bj * 64 + c0);
    const float4 tr =
        *(const float4*)(M + (size_t)(bj * 64 + r) * D + bi * 64 + c0);
    t2[r][c0 + 0] = tr.x; t2[r][c0 + 1] = tr.y;
    t2[r][c0 + 2] = tr.z; t2[r][c0 + 3] = tr.w;
  }
  __syncthreads();
#pragma unroll
  for (int i = 0; i < 4; ++i) {
    const int r = i * 16 + r0;
    const float o[4] = {own[i].x, own[i].y, own[i].z, own[i].w};
    ushort4 hv;
    u16* hp = (u16*)&hv;
#pragma unroll
    for (int j = 0; j < 4; ++j)
      hp[j] = f2bf((o[j] - t2[c0 + j][r]) * EXPM_SCALE);
    *(ushort4*)(X + (size_t)(bi * 64 + r) * D + bj * 64 + c0) = hv;
  }
}

// ---------------------------------------------------------------------------
// generic chain GEMM round + norm tail (r3-proven 64x64 body).
struct CJob {
  const u16 *A, *B;
  const float* C;
  u16 *Dst, *DT;
  float alpha;
};
struct GNParams {
  CJob jobs[2];
  int njobs;
  const float* x;
  u16* Xn;
  int row0;
};
__global__ __launch_bounds__(256) void gemm_norm_kernel(GNParams p) {
  __shared__ __align__(16) u16 ldsA[2][64 * 64];
  __shared__ __align__(16) u16 ldsB[2][64 * 64];
  const int bid = blockIdx.x, tid = threadIdx.x;
  if (bid >= p.njobs) {
    norm_rows8(p.x, p.Xn, p.row0 + (bid - p.njobs) * 8, tid,
               (float*)&ldsA[0][0]);
    return;
  }
  const CJob jb = p.jobs[bid >> 8];
  const int bi = (bid >> 4) & 15, bj = bid & 15;
  const int w = tid >> 6, lane = tid & 63;
  const int wr = w >> 1, wc = w & 1;
  f32x4 acc[2][2];
#pragma unroll
  for (int m = 0; m < 2; ++m)
#pragma unroll
    for (int n = 0; n < 2; ++n) acc[m][n] = f32x4{0.f, 0.f, 0.f, 0.f};
  const int r_l = lane >> 3, c_l = lane & 7;

  auto stage = [&](int buf, int kt) {
    const int k0 = kt * 64;
#pragma unroll
    for (int pp = 0; pp < 2; ++pp) {
      const int row = pp * 32 + w * 8 + r_l;
      const int chunk = c_l ^ (row & 7);  // inverse swizzle on global source
      g2l16(jb.A + (size_t)(bi * 64 + row) * D + k0 + chunk * 8,
            (char*)&ldsA[buf][0] + pp * 4096 + w * 1024);
      g2l16(jb.B + (size_t)(bj * 64 + row) * D + k0 + chunk * 8,
            (char*)&ldsB[buf][0] + pp * 4096 + w * 1024);
    }
  };

  stage(0, 0);
  __syncthreads();
  int buf = 0;
  for (int kt = 0; kt < 16; ++kt) {
    if (kt < 15) stage(buf ^ 1, kt + 1);  // prefetch flies under MFMAs
#pragma unroll
    for (int h = 0; h < 2; ++h) {
      const int kk = h * 32 + (lane >> 4) * 8;
      short8 a[2], b[2];
#pragma unroll
      for (int m = 0; m < 2; ++m) {
        const int row = wr * 32 + m * 16 + (lane & 15);
        const int off = row * 128 + ((kk * 2) ^ ((row & 7) << 4));
        a[m] = *(const short8*)((const char*)&ldsA[buf][0] + off);
      }
#pragma unroll
      for (int n = 0; n < 2; ++n) {
        const int row = wc * 32 + n * 16 + (lane & 15);
        const int off = row * 128 + ((kk * 2) ^ ((row & 7) << 4));
        b[n] = *(const short8*)((const char*)&ldsB[buf][0] + off);
      }
#pragma unroll
      for (int m = 0; m < 2; ++m)
#pragma unroll
        for (int n = 0; n < 2; ++n)
          acc[m][n] = __builtin_amdgcn_mfma_f32_16x16x32_bf16(
              a[m], b[n], acc[m][n], 0, 0, 0);
    }
    __syncthreads();
    buf ^= 1;
  }
  const int or0 = bi * 64 + wr * 32, oc0 = bj * 64 + wc * 32;
#pragma unroll
  for (int m = 0; m < 2; ++m)
#pragma unroll
    for (int n = 0; n < 2; ++n) {
      const int row0 = or0 + m * 16 + (lane >> 4) * 4;
      const int col = oc0 + n * 16 + (lane & 15);
      ushort4 dv;
      u16* dp = (u16*)&dv;
#pragma unroll
      for (int r = 0; r < 4; ++r) {
        float v = acc[m][n][r] * jb.alpha;
        if (jb.C) v += jb.C[(size_t)(row0 + r) * D + col];
        dp[r] = f2bf(v);
        jb.Dst[(size_t)(row0 + r) * D + col] = dp[r];
      }
      if (jb.DT)  // transposed tile: DT[col][row0..row0+3], one 8B store
        *(ushort4*)(jb.DT + (size_t)col * D + row0) = dv;
    }
}

// ---------------------------------------------------------------------------
// L3: fused X3/X4 + buildq + gate + norm tail.
// Block (m, bi, bj): X3 = -f(X2,X), X4 = f(X2,X2) for one 64x64 tile
// (A=X2 staged once); epilogue rounds through bf16 (bit-identical to the
// old separate buildq) and writes X3, X4, q0 (f32), q1t (bf16).
struct X34Params {
  const u16 *X[2], *X2[2];
  u16 *X3[2], *X4[2], *q1t[2];
  float* q0[2];
  const float* qg;
  float* gate_out;
  const float* x;
  u16* Xn;
  int row0;
};
__global__ __launch_bounds__(256) void x34q_norm_kernel(X34Params p) {
  __shared__ __align__(16) u16 ldsA[2][64 * 64];
  __shared__ __align__(16) u16 ldsB1[2][64 * 64];
  __shared__ __align__(16) u16 ldsB2[2][64 * 64];
  const int bid = blockIdx.x, tid = threadIdx.x;
  if (bid > 512) {
    norm_rows8(p.x, p.Xn, p.row0 + (bid - 513) * 8, tid, (float*)&ldsA[0][0]);
    return;
  }
  if (bid == 512) {  // gate softmax
    float* red = (float*)&ldsA[0][0];
    const float4 v = ((const float4*)p.qg)[tid];
    float mx = fmaxf(fmaxf(v.x, v.y), fmaxf(v.z, v.w));
    for (int o = 32; o; o >>= 1) mx = fmaxf(mx, __shfl_xor(mx, o));
    if ((tid & 63) == 0) red[tid >> 6] = mx;
    __syncthreads();
    const float M = fmaxf(fmaxf(red[0], red[1]), fmaxf(red[2], red[3]));
    __syncthreads();
    const float e0 = __expf(v.x - M), e1 = __expf(v.y - M),
                e2 = __expf(v.z - M), e3 = __expf(v.w - M);
    float s = e0 + e1 + e2 + e3;
    for (int o = 32; o; o >>= 1) s += __shfl_xor(s, o);
    if ((tid & 63) == 0) red[tid >> 6] = s;
    __syncthreads();
    const float S = red[0] + red[1] + red[2] + red[3];
    const float4 o4 = {e0 / S, e1 / S, e2 / S, e3 / S};
    ((float4*)p.gate_out)[tid] = o4;
    return;
  }
  const int mz = bid >> 8, t = bid & 255;
  const int bi = t >> 4, bj = t & 15;
  const u16* Ag = p.X2[mz];   // A rows from X2 (bi)
  const u16* B1g = p.X[mz];   // B1 rows from X (bj)
  const u16* B2g = p.X2[mz];  // B2 rows from X2 (bj)
  const int w = tid >> 6, lane = tid & 63;
  const int wr = w >> 1, wc = w & 1;
  f32x4 acc3[2][2], acc4[2][2];
#pragma unroll
  for (int m = 0; m < 2; ++m)
#pragma unroll
    for (int n = 0; n < 2; ++n) {
      acc3[m][n] = f32x4{0.f, 0.f, 0.f, 0.f};
      acc4[m][n] = f32x4{0.f, 0.f, 0.f, 0.f};
    }
  const int r_l = lane >> 3, c_l = lane & 7;

  auto stage = [&](int buf, int kt) {
    const int k0 = kt * 64;
#pragma unroll
    for (int pp = 0; pp < 2; ++pp) {
      const int row = pp * 32 + w * 8 + r_l;
      const int chunk = c_l ^ (row & 7);
      g2l16(Ag + (size_t)(bi * 64 + row) * D + k0 + chunk * 8,
            (char*)&ldsA[buf][0] + pp * 4096 + w * 1024);
      g2l16(B1g + (size_t)(bj * 64 + row) * D + k0 + chunk * 8,
            (char*)&ldsB1[buf][0] + pp * 4096 + w * 1024);
      g2l16(B2g + (size_t)(bj * 64 + row) * D + k0 + chunk * 8,
            (char*)&ldsB2[buf][0] + pp * 4096 + w * 1024);
    }
  };

  stage(0, 0);
  __syncthreads();
  int buf = 0;
  for (int kt = 0; kt < 16; ++kt) {
    if (kt < 15) stage(buf ^ 1, kt + 1);
#pragma unroll
    for (int h = 0; h < 2; ++h) {
      const int kk = h * 32 + (lane >> 4) * 8;
      short8 a[2], b1[2], b2[2];
#pragma unroll
      for (int m = 0; m < 2; ++m) {
        const int row = wr * 32 + m * 16 + (lane & 15);
        const int off = row * 128 + ((kk * 2) ^ ((row & 7) << 4));
        a[m] = *(const short8*)((const char*)&ldsA[buf][0] + off);
      }
#pragma unroll
      for (int n = 0; n < 2; ++n) {
        const int row = wc * 32 + n * 16 + (lane & 15);
        const int off = row * 128 + ((kk * 2) ^ ((row & 7) << 4));
        b1[n] = *(const short8*)((const char*)&ldsB1[buf][0] + off);
        b2[n] = *(const short8*)((const char*)&ldsB2[buf][0] + off);
      }
#pragma unroll
      for (int m = 0; m < 2; ++m)
#pragma unroll
        for (int n = 0; n < 2; ++n) {
          acc3[m][n] = __builtin_amdgcn_mfma_f32_16x16x32_bf16(
              a[m], b1[n], acc3[m][n], 0, 0, 0);
          acc4[m][n] = __builtin_amdgcn_mfma_f32_16x16x32_bf16(
              a[m], b2[n], acc4[m][n], 0, 0, 0);
        }
    }
    __syncthreads();
    buf ^= 1;
  }
  const int or0 = bi * 64 + wr * 32, oc0 = bj * 64 + wc * 32;
#pragma unroll
  for (int m = 0; m < 2; ++m)
#pragma unroll
    for (int n = 0; n < 2; ++n) {
      const int row0 = or0 + m * 16 + (lane >> 4) * 4;
      const int col = oc0 + n * 16 + (lane & 15);
#pragma unroll
      for (int r = 0; r < 4; ++r) {
        const size_t idx = (size_t)(row0 + r) * D + col;
        const u16 x3v = f2bf(-acc3[m][n][r]);
        const u16 x4v = f2bf(acc4[m][n][r]);
        p.X3[mz][idx] = x3v;
        p.X4[mz][idx] = x4v;
        const float d = (row0 + r == col) ? 1.f : 0.f;
        const float xf = bf2f(p.X[mz][idx]);
        const float x2f = bf2f(p.X2[mz][idx]);
        const float x3f = bf2f(x3v), x4f = bf2f(x4v);
        p.q0[mz][idx] = d + xf + x2f * 0.5f + x3f * (1.f / 6.f);
        p.q1t[mz][idx] =
            f2bf(d * (1.f / 24.f) - xf * (1.f / 120.f) + x2f * (1.f / 720.f) -
                 x3f * (1.f / 5040.f) + x4f * (1.f / 40320.f));
      }
    }
}

// ---------------------------------------------------------------------------
// main GEMM: out[r][c] = (f(Xn,W) + bias[c])^2 * gate[c]
// 256x256 tile, BK=32, 8 waves (2x4), 4 LDS bufs (128 KiB), 3-ahead
// prefetch, counted vmcnt(8) before raw s_barrier (no full drains).
__global__ __launch_bounds__(512, 1) void main_gemm_kernel(
    const u16* __restrict__ Xn, const u16* __restrict__ Wm,
    const float* __restrict__ bias, const float* __restrict__ gate,
    float* __restrict__ out) {
  const int tid = threadIdx.x;
  const int wid = tid >> 6, lane = tid & 63;
  const int wr = wid >> 2, wc = wid & 3;   // 2 x 4 waves
  __shared__ u16 lds[4 * 16384];           // 4 bufs x (A 16KB + B 16KB)
  f32x4 acc[8][4];
#pragma unroll
  for (int m = 0; m < 8; ++m)
#pragma unroll
    for (int n = 0; n < 4; ++n) acc[m][n] = f32x4{0.f, 0.f, 0.f, 0.f};

  const int bi = blockIdx.x, bj = blockIdx.y;   // 128 x 4
  const int r_ = tid >> 2;   // 0..127
  const int c_ = tid & 3;

  // stage K-step s into buf s&3. 4 loads/thread (2 A + 2 B).
  auto stage = [&](int s) {
    char* base = (char*)lds + (s & 3) * 32768;
#pragma unroll
    for (int pp = 0; pp < 2; ++pp) {
      const int row = pp * 128 + r_;
      const int csrc = c_ ^ ((row >> 1) & 3);  // inverse swizzle on source
      g2l16(Xn + (size_t)(bi * 256 + row) * D + s * 32 + csrc * 8,
            base + pp * 8192 + tid * 16);
      g2l16(Wm + (size_t)(bj * 256 + row) * D + s * 32 + csrc * 8,
            base + 16384 + pp * 8192 + tid * 16);
    }
  };

  const int h = lane >> 4;  // k-chunk 0..3 within 32-wide step
  auto compute = [&](int s) {
    const char* base = (const char*)lds + (s & 3) * 32768;
    short8 a[8], b[4];
#pragma unroll
    for (int m = 0; m < 8; ++m) {
      const int row = wr * 128 + m * 16 + (lane & 15);
      const int off = row * 64 + ((h ^ ((row >> 1) & 3)) << 4);
      a[m] = *(const short8*)(base + off);
    }
#pragma unroll
    for (int n = 0; n < 4; ++n) {
      const int row = wc * 64 + n * 16 + (lane & 15);
      const int off = 16384 + row * 64 + ((h ^ ((row >> 1) & 3)) << 4);
      b[n] = *(const short8*)(base + off);
    }
    __builtin_amdgcn_s_setprio(1);
#pragma unroll
    for (int m = 0; m < 8; ++m)
#pragma unroll
      for (int n = 0; n < 4; ++n)
        acc[m][n] = __builtin_amdgcn_mfma_f32_16x16x32_bf16(a[m], b[n],
                                                            acc[m][n], 0, 0, 0);
    __builtin_amdgcn_s_setprio(0);
  };

  stage(0); stage(1); stage(2);   // 12 loads in flight
  for (int s = 0; s < 29; ++s) {
    // outstanding: G(s),G(s+1),G(s+2)=12 -> wait to 8 => own G(s) done.
    WAITV(8);
    __builtin_amdgcn_s_barrier();   // now ALL threads' G(s) landed
    __builtin_amdgcn_sched_barrier(0);
    stage(s + 3);  // overwrites buf(s-1): all reads of it done (barrier)
    compute(s);
  }
  WAITV(8);  // outstanding G(29..31)=12
  __builtin_amdgcn_s_barrier();
  __builtin_amdgcn_sched_barrier(0);
  compute(29);
  WAITV(4);  // outstanding G(30),G(31)=8
  __builtin_amdgcn_s_barrier();
  __builtin_amdgcn_sched_barrier(0);
  compute(30);
  WAITV(0);  // outstanding G(31)=4
  __builtin_amdgcn_s_barrier();
  __builtin_amdgcn_sched_barrier(0);
  compute(31);

  const int or0 = bi * 256 + wr * 128, oc0 = bj * 256 + wc * 64;
#pragma unroll
  for (int m = 0; m < 8; ++m)
#pragma unroll
    for (int n = 0; n < 4; ++n) {
      const int col = oc0 + n * 16 + (lane & 15);
      const float bc = bias[col], gc = gate[col];
#pragma unroll
      for (int r = 0; r < 4; ++r) {
        const int row = or0 + m * 16 + (lane >> 4) * 4 + r;
        const float t = acc[m][n][r] + bc;
        out[(size_t)row * D + col] = t * t * gc;
      }
    }
}

// ---------------------------------------------------------------------------
extern "C" void kernel_launch(void* const* d_in, const int* in_sizes, int n_in,
                              void* d_out, int out_size, void* d_ws,
                              size_t ws_size, hipStream_t stream) {
  (void)in_sizes; (void)n_in; (void)out_size; (void)ws_size;
  const float* inp = (const float*)d_in[0];
  const float* Mr = (const float*)d_in[1];
  const float* Mi = (const float*)d_in[2];
  const float* bias = (const float*)d_in[3];
  const float* qg = (const float*)d_in[4];
  float* out = (float*)d_out;
  float* gate_out = out + (size_t)32768 * 1024;

  char* ws = (char*)d_ws;
  u16* Xn = (u16*)ws;  // 64 MB
  // per-matrix region (16 MB): 6 bf16 slots (2 MB) + q0 (4 MB f32).
  // lifetimes: s0 X->E3, s1 X2->Et->E3t, s2 X3->E1, s3 X4->E2,
  //            s4 q1t->E1t, s5 E2t
  auto slot = [&](int m, int s) -> u16* {
    return (u16*)(ws + 67108864 + (size_t)m * 16777216 + (size_t)s * 2097152);
  };
  auto q0p = [&](int m) -> float* {
    return (float*)(ws + 67108864 + (size_t)m * 16777216 + 12582912);
  };
  u16* W = (u16*)(ws + 100663296);  // 96 MB: 2 MB

  // normalize rows: 8 launches x 4096 rows (512 blocks of 8 rows each)
  const int CH = 4096, NB = 512;
  int row0 = 0;

  // L1: skew
  {
    SkewParams sp{Mr, Mi, slot(0, 0), slot(1, 0), inp, Xn, row0};
    skew_norm_kernel<<<512 + NB, 256, 0, stream>>>(sp);
    row0 += CH;
  }
  GNParams gp{};
  gp.x = inp; gp.Xn = Xn;
  // L2: X2 = -f(X,X) -> s1
  for (int m = 0; m < 2; ++m)
    gp.jobs[m] = CJob{slot(m, 0), slot(m, 0), nullptr, slot(m, 1), nullptr,
                      -1.f};
  gp.njobs = 512; gp.row0 = row0;
  gemm_norm_kernel<<<512 + NB, 256, 0, stream>>>(gp);
  row0 += CH;
  // L3: fused X3/X4 + buildq + gate
  {
    X34Params xp{};
    for (int m = 0; m < 2; ++m) {
      xp.X[m] = slot(m, 0); xp.X2[m] = slot(m, 1);
      xp.X3[m] = slot(m, 2); xp.X4[m] = slot(m, 3);
      xp.q1t[m] = slot(m, 4); xp.q0[m] = q0p(m);
    }
    xp.qg = qg; xp.gate_out = gate_out;
    xp.x = inp; xp.Xn = Xn; xp.row0 = row0;
    x34q_norm_kernel<<<513 + NB, 256, 0, stream>>>(xp);
    row0 += CH;
  }
  // L4: E = f(X4, q1t) + q0 -> s0, dual Et -> s1
  for (int m = 0; m < 2; ++m)
    gp.jobs[m] = CJob{slot(m, 3), slot(m, 4), q0p(m), slot(m, 0), slot(m, 1),
                      1.f};
  gp.njobs = 512; gp.row0 = row0;
  gemm_norm_kernel<<<512 + NB, 256, 0, stream>>>(gp);
  row0 += CH;
  // L5: sq1: E1 = f(E,Et) -> s2, dual E1t -> s4
  for (int m = 0; m < 2; ++m)
    gp.jobs[m] = CJob{slot(m, 0), slot(m, 1), nullptr, slot(m, 2), slot(m, 4),
                      1.f};
  gp.row0 = row0;
  gemm_norm_kernel<<<512 + NB, 256, 0, stream>>>(gp);
  row0 += CH;
  // L6: sq2: E2 = f(E1,E1t) -> s3, dual E2t -> s5
  for (int m = 0; m < 2; ++m)
    gp.jobs[m] = CJob{slot(m, 2), slot(m, 4), nullptr, slot(m, 3), slot(m, 5),
                      1.f};
  gp.row0 = row0;
  gemm_norm_kernel<<<512 + NB, 256, 0, stream>>>(gp);
  row0 += CH;
  // L7: sq3: E3 = f(E2,E2t) -> s0, dual E3t -> s1
  for (int m = 0; m < 2; ++m)
    gp.jobs[m] = CJob{slot(m, 3), slot(m, 5), nullptr, slot(m, 0), slot(m, 1),
                      1.f};
  gp.row0 = row0;
  gemm_norm_kernel<<<512 + NB, 256, 0, stream>>>(gp);
  row0 += CH;
  // L8: W = U^T = f(E3t_B, E3_A)
  gp.jobs[0] = CJob{slot(1, 1), slot(0, 0), nullptr, W, nullptr, 1.f};
  gp.njobs = 256; gp.row0 = row0;
  gemm_norm_kernel<<<256 + NB, 256, 0, stream>>>(gp);

  main_gemm_kernel<<<dim3(128, 4), 512, 0, stream>>>(Xn, W, bias, gate_out,
                                                     out);
}

// Round 11
// 228.964 us; speedup vs baseline: 2.7856x; 1.0309x over previous
//
#include <hip/hip_runtime.h>

// ---------------------------------------------------------------------------
// RefinedQuantumEntanglementLayer on MI355X (gfx950)
//
// out = (l2norm(x) @ expm(Mr-Mr^T) @ expm(Mi-Mi^T) + bias)^2 * softmax(qg)
//
// r11: port the r10 counted-vmcnt pipeline (proven bit-exact on the main
// GEMM) to the chain bodies:
//  * gemm_norm: 4 bufs x 16KB (64KB LDS, 2 blocks/CU), 3-ahead prefetch,
//    vmcnt(8) before raw s_barrier, stage(s+3) after barrier, tail 8/4/0.
//  * x34q: 3 bufs x 3 arrays (72KB, 2 blocks/CU), 2-ahead, vmcnt(6),
//    tail 6/0, rotating buf indices.
// K-order and MFMA order unchanged everywhere -> absmax must stay exactly
// 4.172325e-07 (r9/r10 value); deviation = race.
//
// Chain math (deg-8 Paterson-Stockmeyer, s=3):  [f(A,B) = A*B^T]
//   X2 = -f(X,X); X3 = -f(X2,X); X4 = f(X2,X2)
//   q0 = I+X+X2/2+X3/6 (f32); q1t = elementwise-transposed q1 (odd flips)
//   E  = f(X4,q1t)+q0 [dual-write -> Et]
//   squarings E' = f(E,Et) [dual -> E't]; W = U^T = f(E3t_B, E3_A)
// ---------------------------------------------------------------------------

typedef unsigned int u32;
typedef unsigned short u16;
typedef __attribute__((ext_vector_type(8))) short short8;   // 8 x bf16 raw
typedef __attribute__((ext_vector_type(4))) float f32x4;

#define GLOBAL_AS __attribute__((address_space(1)))
#define LDS_AS    __attribute__((address_space(3)))

constexpr int D = 1024;
constexpr float EXPM_SCALE = 1.0f / 8.0f;   // s = 3 squarings

__device__ __forceinline__ u16 f2bf(float f) {
  union { float f; u32 u; } v; v.f = f;
  u32 r = (v.u + 0x7FFFu + ((v.u >> 16) & 1u)) >> 16;
  return (u16)r;
}
__device__ __forceinline__ float bf2f(u16 u) {
  union { u32 u; float f; } v; v.u = ((u32)u) << 16;
  return v.f;
}

// async global->LDS, 16B per lane; lds base must be wave-uniform.
__device__ __forceinline__ void g2l16(const void* g, void* l) {
  __builtin_amdgcn_global_load_lds((const GLOBAL_AS u32*)g, (LDS_AS u32*)l,
                                   16, 0, 0);
}

#define WAITV(N)                                                   \
  do {                                                             \
    asm volatile("s_waitcnt vmcnt(" #N ")" ::: "memory");          \
    __builtin_amdgcn_sched_barrier(0);                             \
  } while (0)

// ---------------------------------------------------------------------------
// normalize 8 rows of x -> bf16 (tail body shared by chain launches)
__device__ void norm_rows8(const float* __restrict__ x, u16* __restrict__ Xn,
                           int r0, int tid, float* sred) {
  float4 v[8];
#pragma unroll
  for (int i = 0; i < 8; ++i)
    v[i] = ((const float4*)(x + (size_t)(r0 + i) * D))[tid];
  float ss[8];
#pragma unroll
  for (int i = 0; i < 8; ++i)
    ss[i] = v[i].x * v[i].x + v[i].y * v[i].y + v[i].z * v[i].z +
            v[i].w * v[i].w;
  for (int o = 32; o; o >>= 1)
#pragma unroll
    for (int i = 0; i < 8; ++i) ss[i] += __shfl_down(ss[i], o);
  const int w = tid >> 6;
  if ((tid & 63) == 0)
#pragma unroll
    for (int i = 0; i < 8; ++i) sred[i * 4 + w] = ss[i];
  __syncthreads();
#pragma unroll
  for (int i = 0; i < 8; ++i) {
    const float tot =
        sred[i * 4 + 0] + sred[i * 4 + 1] + sred[i * 4 + 2] + sred[i * 4 + 3];
    const float inv = rsqrtf(fmaxf(tot, 1e-12f));
    ushort4 o4;
    o4.x = f2bf(v[i].x * inv); o4.y = f2bf(v[i].y * inv);
    o4.z = f2bf(v[i].z * inv); o4.w = f2bf(v[i].w * inv);
    ((ushort4*)(Xn + (size_t)(r0 + i) * D))[tid] = o4;
  }
}

// ---------------------------------------------------------------------------
// L1: skew tiles (512 jobs) + norm tail
struct SkewParams {
  const float *Mr, *Mi;
  u16 *X0, *X1;
  const float* x;
  u16* Xn;
  int row0;
};
__global__ __launch_bounds__(256) void skew_norm_kernel(SkewParams p) {
  __shared__ __align__(16) float t2[64][67];
  const int bid = blockIdx.x, tid = threadIdx.x;
  if (bid >= 512) {
    norm_rows8(p.x, p.Xn, p.row0 + (bid - 512) * 8, tid, &t2[0][0]);
    return;
  }
  const int z = bid >> 8, t = bid & 255;
  const float* M = z ? p.Mi : p.Mr;
  u16* X = z ? p.X1 : p.X0;
  const int bi = t >> 4, bj = t & 15;
  const int r0 = tid >> 4, c0 = (tid & 15) * 4;
  float4 own[4];
#pragma unroll
  for (int i = 0; i < 4; ++i) {
    const int r = i * 16 + r0;
    own[i] = *(const float4*)(M + (size_t)(bi * 64 + r) * D + bj * 64 + c0);
    const float4 tr =
        *(const float4*)(M + (size_t)(bj * 64 + r) * D + bi * 64 + c0);
    t2[r][c0 + 0] = tr.x; t2[r][c0 + 1] = tr.y;
    t2[r][c0 + 2] = tr.z; t2[r][c0 + 3] = tr.w;
  }
  __syncthreads();
#pragma unroll
  for (int i = 0; i < 4; ++i) {
    const int r = i * 16 + r0;
    const float o[4] = {own[i].x, own[i].y, own[i].z, own[i].w};
    ushort4 hv;
    u16* hp = (u16*)&hv;
#pragma unroll
    for (int j = 0; j < 4; ++j)
      hp[j] = f2bf((o[j] - t2[c0 + j][r]) * EXPM_SCALE);
    *(ushort4*)(X + (size_t)(bi * 64 + r) * D + bj * 64 + c0) = hv;
  }
}

// ---------------------------------------------------------------------------
// generic chain GEMM round + norm tail. 64x64 tile, BK=64, 4 waves
// (2x2, 32x32 each), 4 LDS bufs, 3-ahead prefetch, counted vmcnt.
struct CJob {
  const u16 *A, *B;
  const float* C;
  u16 *Dst, *DT;
  float alpha;
};
struct GNParams {
  CJob jobs[2];
  int njobs;
  const float* x;
  u16* Xn;
  int row0;
};
__global__ __launch_bounds__(256) void gemm_norm_kernel(GNParams p) {
  __shared__ __align__(16) u16 ldsA[4][4096];
  __shared__ __align__(16) u16 ldsB[4][4096];
  const int bid = blockIdx.x, tid = threadIdx.x;
  if (bid >= p.njobs) {
    norm_rows8(p.x, p.Xn, p.row0 + (bid - p.njobs) * 8, tid,
               (float*)&ldsA[0][0]);
    return;
  }
  const CJob jb = p.jobs[bid >> 8];
  const int bi = (bid >> 4) & 15, bj = bid & 15;
  const int w = tid >> 6, lane = tid & 63;
  const int wr = w >> 1, wc = w & 1;
  f32x4 acc[2][2];
#pragma unroll
  for (int m = 0; m < 2; ++m)
#pragma unroll
    for (int n = 0; n < 2; ++n) acc[m][n] = f32x4{0.f, 0.f, 0.f, 0.f};
  const int r_l = lane >> 3, c_l = lane & 7;

  auto stage = [&](int buf, int kt) {   // 4 g2l16 per thread
    const int k0 = kt * 64;
#pragma unroll
    for (int pp = 0; pp < 2; ++pp) {
      const int row = pp * 32 + w * 8 + r_l;
      const int chunk = c_l ^ (row & 7);  // inverse swizzle on global source
      g2l16(jb.A + (size_t)(bi * 64 + row) * D + k0 + chunk * 8,
            (char*)&ldsA[buf][0] + pp * 4096 + w * 1024);
      g2l16(jb.B + (size_t)(bj * 64 + row) * D + k0 + chunk * 8,
            (char*)&ldsB[buf][0] + pp * 4096 + w * 1024);
    }
  };
  auto compute = [&](int buf, int kt) {
    (void)kt;
#pragma unroll
    for (int h = 0; h < 2; ++h) {
      const int kk = h * 32 + (lane >> 4) * 8;
      short8 a[2], b[2];
#pragma unroll
      for (int m = 0; m < 2; ++m) {
        const int row = wr * 32 + m * 16 + (lane & 15);
        const int off = row * 128 + ((kk * 2) ^ ((row & 7) << 4));
        a[m] = *(const short8*)((const char*)&ldsA[buf][0] + off);
      }
#pragma unroll
      for (int n = 0; n < 2; ++n) {
        const int row = wc * 32 + n * 16 + (lane & 15);
        const int off = row * 128 + ((kk * 2) ^ ((row & 7) << 4));
        b[n] = *(const short8*)((const char*)&ldsB[buf][0] + off);
      }
#pragma unroll
      for (int m = 0; m < 2; ++m)
#pragma unroll
        for (int n = 0; n < 2; ++n)
          acc[m][n] = __builtin_amdgcn_mfma_f32_16x16x32_bf16(
              a[m], b[n], acc[m][n], 0, 0, 0);
    }
  };

  stage(0, 0); stage(1, 1); stage(2, 2);   // 12 loads in flight
  for (int s = 0; s < 13; ++s) {
    WAITV(8);                              // own G(s) landed
    __builtin_amdgcn_s_barrier();          // all threads' G(s) landed
    __builtin_amdgcn_sched_barrier(0);
    stage((s + 3) & 3, s + 3);             // overwrites buf(s-1): reads done
    compute(s & 3, s);
  }
  WAITV(8);
  __builtin_amdgcn_s_barrier();
  __builtin_amdgcn_sched_barrier(0);
  compute(13 & 3, 13);
  WAITV(4);
  __builtin_amdgcn_s_barrier();
  __builtin_amdgcn_sched_barrier(0);
  compute(14 & 3, 14);
  WAITV(0);
  __builtin_amdgcn_s_barrier();
  __builtin_amdgcn_sched_barrier(0);
  compute(15 & 3, 15);

  const int or0 = bi * 64 + wr * 32, oc0 = bj * 64 + wc * 32;
#pragma unroll
  for (int m = 0; m < 2; ++m)
#pragma unroll
    for (int n = 0; n < 2; ++n) {
      const int row0 = or0 + m * 16 + (lane >> 4) * 4;
      const int col = oc0 + n * 16 + (lane & 15);
      ushort4 dv;
      u16* dp = (u16*)&dv;
#pragma unroll
      for (int r = 0; r < 4; ++r) {
        float v = acc[m][n][r] * jb.alpha;
        if (jb.C) v += jb.C[(size_t)(row0 + r) * D + col];
        dp[r] = f2bf(v);
        jb.Dst[(size_t)(row0 + r) * D + col] = dp[r];
      }
      if (jb.DT)  // transposed tile: DT[col][row0..row0+3], one 8B store
        *(ushort4*)(jb.DT + (size_t)col * D + row0) = dv;
    }
}

// ---------------------------------------------------------------------------
// L3: fused X3/X4 + buildq + gate + norm tail. 3 bufs x 3 arrays (72KB),
// 2-ahead prefetch, counted vmcnt(6).
struct X34Params {
  const u16 *X[2], *X2[2];
  u16 *X3[2], *X4[2], *q1t[2];
  float* q0[2];
  const float* qg;
  float* gate_out;
  const float* x;
  u16* Xn;
  int row0;
};
__global__ __launch_bounds__(256) void x34q_norm_kernel(X34Params p) {
  __shared__ __align__(16) u16 ldsA[3][4096];
  __shared__ __align__(16) u16 ldsB1[3][4096];
  __shared__ __align__(16) u16 ldsB2[3][4096];
  const int bid = blockIdx.x, tid = threadIdx.x;
  if (bid > 512) {
    norm_rows8(p.x, p.Xn, p.row0 + (bid - 513) * 8, tid, (float*)&ldsA[0][0]);
    return;
  }
  if (bid == 512) {  // gate softmax
    float* red = (float*)&ldsA[0][0];
    const float4 v = ((const float4*)p.qg)[tid];
    float mx = fmaxf(fmaxf(v.x, v.y), fmaxf(v.z, v.w));
    for (int o = 32; o; o >>= 1) mx = fmaxf(mx, __shfl_xor(mx, o));
    if ((tid & 63) == 0) red[tid >> 6] = mx;
    __syncthreads();
    const float M = fmaxf(fmaxf(red[0], red[1]), fmaxf(red[2], red[3]));
    __syncthreads();
    const float e0 = __expf(v.x - M), e1 = __expf(v.y - M),
                e2 = __expf(v.z - M), e3 = __expf(v.w - M);
    float s = e0 + e1 + e2 + e3;
    for (int o = 32; o; o >>= 1) s += __shfl_xor(s, o);
    if ((tid & 63) == 0) red[tid >> 6] = s;
    __syncthreads();
    const float S = red[0] + red[1] + red[2] + red[3];
    const float4 o4 = {e0 / S, e1 / S, e2 / S, e3 / S};
    ((float4*)p.gate_out)[tid] = o4;
    return;
  }
  const int mz = bid >> 8, t = bid & 255;
  const int bi = t >> 4, bj = t & 15;
  const u16* Ag = p.X2[mz];
  const u16* B1g = p.X[mz];
  const u16* B2g = p.X2[mz];
  const int w = tid >> 6, lane = tid & 63;
  const int wr = w >> 1, wc = w & 1;
  f32x4 acc3[2][2], acc4[2][2];
#pragma unroll
  for (int m = 0; m < 2; ++m)
#pragma unroll
    for (int n = 0; n < 2; ++n) {
      acc3[m][n] = f32x4{0.f, 0.f, 0.f, 0.f};
      acc4[m][n] = f32x4{0.f, 0.f, 0.f, 0.f};
    }
  const int r_l = lane >> 3, c_l = lane & 7;

  auto stage = [&](int buf, int kt) {   // 6 g2l16 per thread
    const int k0 = kt * 64;
#pragma unroll
    for (int pp = 0; pp < 2; ++pp) {
      const int row = pp * 32 + w * 8 + r_l;
      const int chunk = c_l ^ (row & 7);
      g2l16(Ag + (size_t)(bi * 64 + row) * D + k0 + chunk * 8,
            (char*)&ldsA[buf][0] + pp * 4096 + w * 1024);
      g2l16(B1g + (size_t)(bj * 64 + row) * D + k0 + chunk * 8,
            (char*)&ldsB1[buf][0] + pp * 4096 + w * 1024);
      g2l16(B2g + (size_t)(bj * 64 + row) * D + k0 + chunk * 8,
            (char*)&ldsB2[buf][0] + pp * 4096 + w * 1024);
    }
  };
  auto compute = [&](int buf, int kt) {
    (void)kt;
#pragma unroll
    for (int h = 0; h < 2; ++h) {
      const int kk = h * 32 + (lane >> 4) * 8;
      short8 a[2], b1[2], b2[2];
#pragma unroll
      for (int m = 0; m < 2; ++m) {
        const int row = wr * 32 + m * 16 + (lane & 15);
        const int off = row * 128 + ((kk * 2) ^ ((row & 7) << 4));
        a[m] = *(const short8*)((const char*)&ldsA[buf][0] + off);
      }
#pragma unroll
      for (int n = 0; n < 2; ++n) {
        const int row = wc * 32 + n * 16 + (lane & 15);
        const int off = row * 128 + ((kk * 2) ^ ((row & 7) << 4));
        b1[n] = *(const short8*)((const char*)&ldsB1[buf][0] + off);
        b2[n] = *(const short8*)((const char*)&ldsB2[buf][0] + off);
      }
#pragma unroll
      for (int m = 0; m < 2; ++m)
#pragma unroll
        for (int n = 0; n < 2; ++n) {
          acc3[m][n] = __builtin_amdgcn_mfma_f32_16x16x32_bf16(
              a[m], b1[n], acc3[m][n], 0, 0, 0);
          acc4[m][n] = __builtin_amdgcn_mfma_f32_16x16x32_bf16(
              a[m], b2[n], acc4[m][n], 0, 0, 0);
        }
    }
  };

  stage(0, 0); stage(1, 1);   // 12 loads in flight
  int c0 = 0, c1 = 1, c2 = 2;
  for (int s = 0; s < 14; ++s) {
    WAITV(6);                              // own G(s) landed
    __builtin_amdgcn_s_barrier();
    __builtin_amdgcn_sched_barrier(0);
    stage(c2, s + 2);                      // overwrites buf(s-1)
    compute(c0, s);
    const int tswap = c0; c0 = c1; c1 = c2; c2 = tswap;
  }
  WAITV(6);
  __builtin_amdgcn_s_barrier();
  __builtin_amdgcn_sched_barrier(0);
  compute(c0, 14);
  WAITV(0);
  __builtin_amdgcn_s_barrier();
  __builtin_amdgcn_sched_barrier(0);
  compute(c1, 15);

  const int or0 = bi * 64 + wr * 32, oc0 = bj * 64 + wc * 32;
#pragma unroll
  for (int m = 0; m < 2; ++m)
#pragma unroll
    for (int n = 0; n < 2; ++n) {
      const int row0 = or0 + m * 16 + (lane >> 4) * 4;
      const int col = oc0 + n * 16 + (lane & 15);
#pragma unroll
      for (int r = 0; r < 4; ++r) {
        const size_t idx = (size_t)(row0 + r) * D + col;
        const u16 x3v = f2bf(-acc3[m][n][r]);
        const u16 x4v = f2bf(acc4[m][n][r]);
        p.X3[mz][idx] = x3v;
        p.X4[mz][idx] = x4v;
        const float d = (row0 + r == col) ? 1.f : 0.f;
        const float xf = bf2f(p.X[mz][idx]);
        const float x2f = bf2f(p.X2[mz][idx]);
        const float x3f = bf2f(x3v), x4f = bf2f(x4v);
        p.q0[mz][idx] = d + xf + x2f * 0.5f + x3f * (1.f / 6.f);
        p.q1t[mz][idx] =
            f2bf(d * (1.f / 24.f) - xf * (1.f / 120.f) + x2f * (1.f / 720.f) -
                 x3f * (1.f / 5040.f) + x4f * (1.f / 40320.f));
      }
    }
}

// ---------------------------------------------------------------------------
// main GEMM (r10, unchanged): out[r][c] = (f(Xn,W) + bias[c])^2 * gate[c]
// 256x256 tile, BK=32, 8 waves (2x4), 4 LDS bufs (128 KiB), 3-ahead
// prefetch, counted vmcnt(8) before raw s_barrier (no full drains).
__global__ __launch_bounds__(512, 1) void main_gemm_kernel(
    const u16* __restrict__ Xn, const u16* __restrict__ Wm,
    const float* __restrict__ bias, const float* __restrict__ gate,
    float* __restrict__ out) {
  const int tid = threadIdx.x;
  const int wid = tid >> 6, lane = tid & 63;
  const int wr = wid >> 2, wc = wid & 3;   // 2 x 4 waves
  __shared__ u16 lds[4 * 16384];           // 4 bufs x (A 16KB + B 16KB)
  f32x4 acc[8][4];
#pragma unroll
  for (int m = 0; m < 8; ++m)
#pragma unroll
    for (int n = 0; n < 4; ++n) acc[m][n] = f32x4{0.f, 0.f, 0.f, 0.f};

  const int bi = blockIdx.x, bj = blockIdx.y;   // 128 x 4
  const int r_ = tid >> 2;   // 0..127
  const int c_ = tid & 3;

  auto stage = [&](int s) {
    char* base = (char*)lds + (s & 3) * 32768;
#pragma unroll
    for (int pp = 0; pp < 2; ++pp) {
      const int row = pp * 128 + r_;
      const int csrc = c_ ^ ((row >> 1) & 3);  // inverse swizzle on source
      g2l16(Xn + (size_t)(bi * 256 + row) * D + s * 32 + csrc * 8,
            base + pp * 8192 + tid * 16);
      g2l16(Wm + (size_t)(bj * 256 + row) * D + s * 32 + csrc * 8,
            base + 16384 + pp * 8192 + tid * 16);
    }
  };

  const int h = lane >> 4;  // k-chunk 0..3 within 32-wide step
  auto compute = [&](int s) {
    const char* base = (const char*)lds + (s & 3) * 32768;
    short8 a[8], b[4];
#pragma unroll
    for (int m = 0; m < 8; ++m) {
      const int row = wr * 128 + m * 16 + (lane & 15);
      const int off = row * 64 + ((h ^ ((row >> 1) & 3)) << 4);
      a[m] = *(const short8*)(base + off);
    }
#pragma unroll
    for (int n = 0; n < 4; ++n) {
      const int row = wc * 64 + n * 16 + (lane & 15);
      const int off = 16384 + row * 64 + ((h ^ ((row >> 1) & 3)) << 4);
      b[n] = *(const short8*)(base + off);
    }
    __builtin_amdgcn_s_setprio(1);
#pragma unroll
    for (int m = 0; m < 8; ++m)
#pragma unroll
      for (int n = 0; n < 4; ++n)
        acc[m][n] = __builtin_amdgcn_mfma_f32_16x16x32_bf16(a[m], b[n],
                                                            acc[m][n], 0, 0, 0);
    __builtin_amdgcn_s_setprio(0);
  };

  stage(0); stage(1); stage(2);   // 12 loads in flight
  for (int s = 0; s < 29; ++s) {
    WAITV(8);
    __builtin_amdgcn_s_barrier();
    __builtin_amdgcn_sched_barrier(0);
    stage(s + 3);
    compute(s);
  }
  WAITV(8);
  __builtin_amdgcn_s_barrier();
  __builtin_amdgcn_sched_barrier(0);
  compute(29);
  WAITV(4);
  __builtin_amdgcn_s_barrier();
  __builtin_amdgcn_sched_barrier(0);
  compute(30);
  WAITV(0);
  __builtin_amdgcn_s_barrier();
  __builtin_amdgcn_sched_barrier(0);
  compute(31);

  const int or0 = bi * 256 + wr * 128, oc0 = bj * 256 + wc * 64;
#pragma unroll
  for (int m = 0; m < 8; ++m)
#pragma unroll
    for (int n = 0; n < 4; ++n) {
      const int col = oc0 + n * 16 + (lane & 15);
      const float bc = bias[col], gc = gate[col];
#pragma unroll
      for (int r = 0; r < 4; ++r) {
        const int row = or0 + m * 16 + (lane >> 4) * 4 + r;
        const float t = acc[m][n][r] + bc;
        out[(size_t)row * D + col] = t * t * gc;
      }
    }
}

// ---------------------------------------------------------------------------
extern "C" void kernel_launch(void* const* d_in, const int* in_sizes, int n_in,
                              void* d_out, int out_size, void* d_ws,
                              size_t ws_size, hipStream_t stream) {
  (void)in_sizes; (void)n_in; (void)out_size; (void)ws_size;
  const float* inp = (const float*)d_in[0];
  const float* Mr = (const float*)d_in[1];
  const float* Mi = (const float*)d_in[2];
  const float* bias = (const float*)d_in[3];
  const float* qg = (const float*)d_in[4];
  float* out = (float*)d_out;
  float* gate_out = out + (size_t)32768 * 1024;

  char* ws = (char*)d_ws;
  u16* Xn = (u16*)ws;  // 64 MB
  // per-matrix region (16 MB): 6 bf16 slots (2 MB) + q0 (4 MB f32).
  // lifetimes: s0 X->E3, s1 X2->Et->E3t, s2 X3->E1, s3 X4->E2,
  //            s4 q1t->E1t, s5 E2t
  auto slot = [&](int m, int s) -> u16* {
    return (u16*)(ws + 67108864 + (size_t)m * 16777216 + (size_t)s * 2097152);
  };
  auto q0p = [&](int m) -> float* {
    return (float*)(ws + 67108864 + (size_t)m * 16777216 + 12582912);
  };
  u16* W = (u16*)(ws + 100663296);  // 96 MB: 2 MB

  // normalize rows: 8 launches x 4096 rows (512 blocks of 8 rows each)
  const int CH = 4096, NB = 512;
  int row0 = 0;

  // L1: skew
  {
    SkewParams sp{Mr, Mi, slot(0, 0), slot(1, 0), inp, Xn, row0};
    skew_norm_kernel<<<512 + NB, 256, 0, stream>>>(sp);
    row0 += CH;
  }
  GNParams gp{};
  gp.x = inp; gp.Xn = Xn;
  // L2: X2 = -f(X,X) -> s1
  for (int m = 0; m < 2; ++m)
    gp.jobs[m] = CJob{slot(m, 0), slot(m, 0), nullptr, slot(m, 1), nullptr,
                      -1.f};
  gp.njobs = 512; gp.row0 = row0;
  gemm_norm_kernel<<<512 + NB, 256, 0, stream>>>(gp);
  row0 += CH;
  // L3: fused X3/X4 + buildq + gate
  {
    X34Params xp{};
    for (int m = 0; m < 2; ++m) {
      xp.X[m] = slot(m, 0); xp.X2[m] = slot(m, 1);
      xp.X3[m] = slot(m, 2); xp.X4[m] = slot(m, 3);
      xp.q1t[m] = slot(m, 4); xp.q0[m] = q0p(m);
    }
    xp.qg = qg; xp.gate_out = gate_out;
    xp.x = inp; xp.Xn = Xn; xp.row0 = row0;
    x34q_norm_kernel<<<513 + NB, 256, 0, stream>>>(xp);
    row0 += CH;
  }
  // L4: E = f(X4, q1t) + q0 -> s0, dual Et -> s1
  for (int m = 0; m < 2; ++m)
    gp.jobs[m] = CJob{slot(m, 3), slot(m, 4), q0p(m), slot(m, 0), slot(m, 1),
                      1.f};
  gp.njobs = 512; gp.row0 = row0;
  gemm_norm_kernel<<<512 + NB, 256, 0, stream>>>(gp);
  row0 += CH;
  // L5: sq1: E1 = f(E,Et) -> s2, dual E1t -> s4
  for (int m = 0; m < 2; ++m)
    gp.jobs[m] = CJob{slot(m, 0), slot(m, 1), nullptr, slot(m, 2), slot(m, 4),
                      1.f};
  gp.row0 = row0;
  gemm_norm_kernel<<<512 + NB, 256, 0, stream>>>(gp);
  row0 += CH;
  // L6: sq2: E2 = f(E1,E1t) -> s3, dual E2t -> s5
  for (int m = 0; m < 2; ++m)
    gp.jobs[m] = CJob{slot(m, 2), slot(m, 4), nullptr, slot(m, 3), slot(m, 5),
                      1.f};
  gp.row0 = row0;
  gemm_norm_kernel<<<512 + NB, 256, 0, stream>>>(gp);
  row0 += CH;
  // L7: sq3: E3 = f(E2,E2t) -> s0, dual E3t -> s1
  for (int m = 0; m < 2; ++m)
    gp.jobs[m] = CJob{slot(m, 3), slot(m, 5), nullptr, slot(m, 0), slot(m, 1),
                      1.f};
  gp.row0 = row0;
  gemm_norm_kernel<<<512 + NB, 256, 0, stream>>>(gp);
  row0 += CH;
  // L8: W = U^T = f(E3t_B, E3_A)
  gp.jobs[0] = CJob{slot(1, 1), slot(0, 0), nullptr, W, nullptr, 1.f};
  gp.njobs = 256; gp.row0 = row0;
  gemm_norm_kernel<<<256 + NB, 256, 0, stream>>>(gp);

  main_gemm_kernel<<<dim3(128, 4), 512, 0, stream>>>(Xn, W, bias, gate_out,
                                                     out);
}

// Round 12
// 217.675 us; speedup vs baseline: 2.9301x; 1.0519x over previous
//
#include <hip/hip_runtime.h>

// ---------------------------------------------------------------------------
// RefinedQuantumEntanglementLayer on MI355X (gfx950)
//
// out = (l2norm(x) @ expm(Mr-Mr^T) @ expm(Mi-Mi^T) + bias)^2 * softmax(qg)
//
// r12: shrink chain-kernel LDS so the folded normalize tails CO-SCHEDULE
// with the GEMM blocks (r11 diagnosis: 64KB/block capped residency at
// 2/CU, so the 512 norm blocks ran as a serial second wave per launch).
//  * gemm_norm: 3 bufs (48KB) -> 3 blocks/CU; 2-ahead, WAITV(4), tail 4/0.
//  * x34q: BK=32, 3 arrays x 3 bufs x 4KB = 36KB -> 4 blocks/CU; 2-ahead,
//    WAITV(3), tail 3/0; swizzle chunk^=(row&3) -> 2-way banks (free).
// K ascends in the same 32-wide chunks everywhere -> accumulation order
// bit-identical -> absmax must stay exactly 4.172325e-07.
//
// Chain math (deg-8 Paterson-Stockmeyer, s=3):  [f(A,B) = A*B^T]
//   X2 = -f(X,X); X3 = -f(X2,X); X4 = f(X2,X2)
//   q0 = I+X+X2/2+X3/6 (f32); q1t = elementwise-transposed q1 (odd flips)
//   E  = f(X4,q1t)+q0 [dual-write -> Et]
//   squarings E' = f(E,Et) [dual -> E't]; W = U^T = f(E3t_B, E3_A)
// main (r10, unchanged): 256^2 tile BK=32 4-buf counted-vmcnt pipeline.
// ---------------------------------------------------------------------------

typedef unsigned int u32;
typedef unsigned short u16;
typedef __attribute__((ext_vector_type(8))) short short8;   // 8 x bf16 raw
typedef __attribute__((ext_vector_type(4))) float f32x4;

#define GLOBAL_AS __attribute__((address_space(1)))
#define LDS_AS    __attribute__((address_space(3)))

constexpr int D = 1024;
constexpr float EXPM_SCALE = 1.0f / 8.0f;   // s = 3 squarings

__device__ __forceinline__ u16 f2bf(float f) {
  union { float f; u32 u; } v; v.f = f;
  u32 r = (v.u + 0x7FFFu + ((v.u >> 16) & 1u)) >> 16;
  return (u16)r;
}
__device__ __forceinline__ float bf2f(u16 u) {
  union { u32 u; float f; } v; v.u = ((u32)u) << 16;
  return v.f;
}

// async global->LDS, 16B per lane; lds base must be wave-uniform.
__device__ __forceinline__ void g2l16(const void* g, void* l) {
  __builtin_amdgcn_global_load_lds((const GLOBAL_AS u32*)g, (LDS_AS u32*)l,
                                   16, 0, 0);
}

#define WAITV(N)                                                   \
  do {                                                             \
    asm volatile("s_waitcnt vmcnt(" #N ")" ::: "memory");          \
    __builtin_amdgcn_sched_barrier(0);                             \
  } while (0)

// ---------------------------------------------------------------------------
// normalize 8 rows of x -> bf16 (tail body shared by chain launches)
__device__ void norm_rows8(const float* __restrict__ x, u16* __restrict__ Xn,
                           int r0, int tid, float* sred) {
  float4 v[8];
#pragma unroll
  for (int i = 0; i < 8; ++i)
    v[i] = ((const float4*)(x + (size_t)(r0 + i) * D))[tid];
  float ss[8];
#pragma unroll
  for (int i = 0; i < 8; ++i)
    ss[i] = v[i].x * v[i].x + v[i].y * v[i].y + v[i].z * v[i].z +
            v[i].w * v[i].w;
  for (int o = 32; o; o >>= 1)
#pragma unroll
    for (int i = 0; i < 8; ++i) ss[i] += __shfl_down(ss[i], o);
  const int w = tid >> 6;
  if ((tid & 63) == 0)
#pragma unroll
    for (int i = 0; i < 8; ++i) sred[i * 4 + w] = ss[i];
  __syncthreads();
#pragma unroll
  for (int i = 0; i < 8; ++i) {
    const float tot =
        sred[i * 4 + 0] + sred[i * 4 + 1] + sred[i * 4 + 2] + sred[i * 4 + 3];
    const float inv = rsqrtf(fmaxf(tot, 1e-12f));
    ushort4 o4;
    o4.x = f2bf(v[i].x * inv); o4.y = f2bf(v[i].y * inv);
    o4.z = f2bf(v[i].z * inv); o4.w = f2bf(v[i].w * inv);
    ((ushort4*)(Xn + (size_t)(r0 + i) * D))[tid] = o4;
  }
}

// ---------------------------------------------------------------------------
// L1: skew tiles (512 jobs) + norm tail
struct SkewParams {
  const float *Mr, *Mi;
  u16 *X0, *X1;
  const float* x;
  u16* Xn;
  int row0;
};
__global__ __launch_bounds__(256) void skew_norm_kernel(SkewParams p) {
  __shared__ __align__(16) float t2[64][67];
  const int bid = blockIdx.x, tid = threadIdx.x;
  if (bid >= 512) {
    norm_rows8(p.x, p.Xn, p.row0 + (bid - 512) * 8, tid, &t2[0][0]);
    return;
  }
  const int z = bid >> 8, t = bid & 255;
  const float* M = z ? p.Mi : p.Mr;
  u16* X = z ? p.X1 : p.X0;
  const int bi = t >> 4, bj = t & 15;
  const int r0 = tid >> 4, c0 = (tid & 15) * 4;
  float4 own[4];
#pragma unroll
  for (int i = 0; i < 4; ++i) {
    const int r = i * 16 + r0;
    own[i] = *(const float4*)(M + (size_t)(bi * 64 + r) * D + bj * 64 + c0);
    const float4 tr =
        *(const float4*)(M + (size_t)(bj * 64 + r) * D + bi * 64 + c0);
    t2[r][c0 + 0] = tr.x; t2[r][c0 + 1] = tr.y;
    t2[r][c0 + 2] = tr.z; t2[r][c0 + 3] = tr.w;
  }
  __syncthreads();
#pragma unroll
  for (int i = 0; i < 4; ++i) {
    const int r = i * 16 + r0;
    const float o[4] = {own[i].x, own[i].y, own[i].z, own[i].w};
    ushort4 hv;
    u16* hp = (u16*)&hv;
#pragma unroll
    for (int j = 0; j < 4; ++j)
      hp[j] = f2bf((o[j] - t2[c0 + j][r]) * EXPM_SCALE);
    *(ushort4*)(X + (size_t)(bi * 64 + r) * D + bj * 64 + c0) = hv;
  }
}

// ---------------------------------------------------------------------------
// generic chain GEMM round + norm tail. 64x64 tile, BK=64, 4 waves
// (2x2, 32x32 each), 3 LDS bufs (48KB -> 3 blocks/CU), 2-ahead prefetch,
// counted vmcnt(4), tail 4/0.
struct CJob {
  const u16 *A, *B;
  const float* C;
  u16 *Dst, *DT;
  float alpha;
};
struct GNParams {
  CJob jobs[2];
  int njobs;
  const float* x;
  u16* Xn;
  int row0;
};
__global__ __launch_bounds__(256) void gemm_norm_kernel(GNParams p) {
  __shared__ __align__(16) u16 ldsA[3][4096];
  __shared__ __align__(16) u16 ldsB[3][4096];
  const int bid = blockIdx.x, tid = threadIdx.x;
  if (bid >= p.njobs) {
    norm_rows8(p.x, p.Xn, p.row0 + (bid - p.njobs) * 8, tid,
               (float*)&ldsA[0][0]);
    return;
  }
  const CJob jb = p.jobs[bid >> 8];
  const int bi = (bid >> 4) & 15, bj = bid & 15;
  const int w = tid >> 6, lane = tid & 63;
  const int wr = w >> 1, wc = w & 1;
  f32x4 acc[2][2];
#pragma unroll
  for (int m = 0; m < 2; ++m)
#pragma unroll
    for (int n = 0; n < 2; ++n) acc[m][n] = f32x4{0.f, 0.f, 0.f, 0.f};
  const int r_l = lane >> 3, c_l = lane & 7;

  auto stage = [&](int buf, int kt) {   // 4 g2l16 per thread
    const int k0 = kt * 64;
#pragma unroll
    for (int pp = 0; pp < 2; ++pp) {
      const int row = pp * 32 + w * 8 + r_l;
      const int chunk = c_l ^ (row & 7);  // inverse swizzle on global source
      g2l16(jb.A + (size_t)(bi * 64 + row) * D + k0 + chunk * 8,
            (char*)&ldsA[buf][0] + pp * 4096 + w * 1024);
      g2l16(jb.B + (size_t)(bj * 64 + row) * D + k0 + chunk * 8,
            (char*)&ldsB[buf][0] + pp * 4096 + w * 1024);
    }
  };
  auto compute = [&](int buf) {
#pragma unroll
    for (int h = 0; h < 2; ++h) {
      const int kk = h * 32 + (lane >> 4) * 8;
      short8 a[2], b[2];
#pragma unroll
      for (int m = 0; m < 2; ++m) {
        const int row = wr * 32 + m * 16 + (lane & 15);
        const int off = row * 128 + ((kk * 2) ^ ((row & 7) << 4));
        a[m] = *(const short8*)((const char*)&ldsA[buf][0] + off);
      }
#pragma unroll
      for (int n = 0; n < 2; ++n) {
        const int row = wc * 32 + n * 16 + (lane & 15);
        const int off = row * 128 + ((kk * 2) ^ ((row & 7) << 4));
        b[n] = *(const short8*)((const char*)&ldsB[buf][0] + off);
      }
#pragma unroll
      for (int m = 0; m < 2; ++m)
#pragma unroll
        for (int n = 0; n < 2; ++n)
          acc[m][n] = __builtin_amdgcn_mfma_f32_16x16x32_bf16(
              a[m], b[n], acc[m][n], 0, 0, 0);
    }
  };

  stage(0, 0); stage(1, 1);   // 8 loads in flight (2-ahead)
  for (int s = 0; s < 14; ++s) {
    WAITV(4);                         // own G(s) landed (G(s+1) may fly)
    __builtin_amdgcn_s_barrier();     // all threads' G(s) landed;
    __builtin_amdgcn_sched_barrier(0);//  all threads finished compute(s-1)
    stage((s + 2) % 3, s + 2);        // overwrites buf(s-1): reads done
    compute(s % 3);
  }
  WAITV(4);
  __builtin_amdgcn_s_barrier();
  __builtin_amdgcn_sched_barrier(0);
  compute(14 % 3);
  WAITV(0);
  __builtin_amdgcn_s_barrier();
  __builtin_amdgcn_sched_barrier(0);
  compute(15 % 3);

  const int or0 = bi * 64 + wr * 32, oc0 = bj * 64 + wc * 32;
#pragma unroll
  for (int m = 0; m < 2; ++m)
#pragma unroll
    for (int n = 0; n < 2; ++n) {
      const int row0 = or0 + m * 16 + (lane >> 4) * 4;
      const int col = oc0 + n * 16 + (lane & 15);
      ushort4 dv;
      u16* dp = (u16*)&dv;
#pragma unroll
      for (int r = 0; r < 4; ++r) {
        float v = acc[m][n][r] * jb.alpha;
        if (jb.C) v += jb.C[(size_t)(row0 + r) * D + col];
        dp[r] = f2bf(v);
        jb.Dst[(size_t)(row0 + r) * D + col] = dp[r];
      }
      if (jb.DT)  // transposed tile: DT[col][row0..row0+3], one 8B store
        *(ushort4*)(jb.DT + (size_t)col * D + row0) = dv;
    }
}

// ---------------------------------------------------------------------------
// L3: fused X3/X4 + buildq + gate + norm tail. BK=32, 3 arrays x 3 bufs
// x 4KB = 36KB (4 blocks/CU), 2-ahead, counted vmcnt(3), tail 3/0.
// Swizzle chunk ^= (row&3): worst-case 2-way bank alias (free).
struct X34Params {
  const u16 *X[2], *X2[2];
  u16 *X3[2], *X4[2], *q1t[2];
  float* q0[2];
  const float* qg;
  float* gate_out;
  const float* x;
  u16* Xn;
  int row0;
};
__global__ __launch_bounds__(256) void x34q_norm_kernel(X34Params p) {
  __shared__ __align__(16) u16 ldsA[3][2048];
  __shared__ __align__(16) u16 ldsB1[3][2048];
  __shared__ __align__(16) u16 ldsB2[3][2048];
  const int bid = blockIdx.x, tid = threadIdx.x;
  if (bid > 512) {
    norm_rows8(p.x, p.Xn, p.row0 + (bid - 513) * 8, tid, (float*)&ldsA[0][0]);
    return;
  }
  if (bid == 512) {  // gate softmax
    float* red = (float*)&ldsA[0][0];
    const float4 v = ((const float4*)p.qg)[tid];
    float mx = fmaxf(fmaxf(v.x, v.y), fmaxf(v.z, v.w));
    for (int o = 32; o; o >>= 1) mx = fmaxf(mx, __shfl_xor(mx, o));
    if ((tid & 63) == 0) red[tid >> 6] = mx;
    __syncthreads();
    const float M = fmaxf(fmaxf(red[0], red[1]), fmaxf(red[2], red[3]));
    __syncthreads();
    const float e0 = __expf(v.x - M), e1 = __expf(v.y - M),
                e2 = __expf(v.z - M), e3 = __expf(v.w - M);
    float s = e0 + e1 + e2 + e3;
    for (int o = 32; o; o >>= 1) s += __shfl_xor(s, o);
    if ((tid & 63) == 0) red[tid >> 6] = s;
    __syncthreads();
    const float S = red[0] + red[1] + red[2] + red[3];
    const float4 o4 = {e0 / S, e1 / S, e2 / S, e3 / S};
    ((float4*)p.gate_out)[tid] = o4;
    return;
  }
  const int mz = bid >> 8, t = bid & 255;
  const int bi = t >> 4, bj = t & 15;
  const u16* Ag = p.X2[mz];
  const u16* B1g = p.X[mz];
  const u16* B2g = p.X2[mz];
  const int w = tid >> 6, lane = tid & 63;
  const int wr = w >> 1, wc = w & 1;
  f32x4 acc3[2][2], acc4[2][2];
#pragma unroll
  for (int m = 0; m < 2; ++m)
#pragma unroll
    for (int n = 0; n < 2; ++n) {
      acc3[m][n] = f32x4{0.f, 0.f, 0.f, 0.f};
      acc4[m][n] = f32x4{0.f, 0.f, 0.f, 0.f};
    }
  const int srow = tid >> 2, sc = tid & 3;   // stage: row 0..63, chunk 0..3

  auto stage = [&](int buf, int s) {   // 3 g2l16 per thread (one per array)
    const int k0 = s * 32;
    const int csrc = sc ^ (srow & 3);  // inverse swizzle on global source
    g2l16(Ag + (size_t)(bi * 64 + srow) * D + k0 + csrc * 8,
          (char*)&ldsA[buf][0] + tid * 16);
    g2l16(B1g + (size_t)(bj * 64 + srow) * D + k0 + csrc * 8,
          (char*)&ldsB1[buf][0] + tid * 16);
    g2l16(B2g + (size_t)(bj * 64 + srow) * D + k0 + csrc * 8,
          (char*)&ldsB2[buf][0] + tid * 16);
  };
  const int h4 = lane >> 4;  // 8-elem chunk within the 32-wide K step
  auto compute = [&](int buf) {
    short8 a[2], b1[2], b2[2];
#pragma unroll
    for (int m = 0; m < 2; ++m) {
      const int row = wr * 32 + m * 16 + (lane & 15);
      const int off = row * 64 + ((h4 ^ (row & 3)) << 4);
      a[m] = *(const short8*)((const char*)&ldsA[buf][0] + off);
    }
#pragma unroll
    for (int n = 0; n < 2; ++n) {
      const int row = wc * 32 + n * 16 + (lane & 15);
      const int off = row * 64 + ((h4 ^ (row & 3)) << 4);
      b1[n] = *(const short8*)((const char*)&ldsB1[buf][0] + off);
      b2[n] = *(const short8*)((const char*)&ldsB2[buf][0] + off);
    }
#pragma unroll
    for (int m = 0; m < 2; ++m)
#pragma unroll
      for (int n = 0; n < 2; ++n) {
        acc3[m][n] = __builtin_amdgcn_mfma_f32_16x16x32_bf16(
            a[m], b1[n], acc3[m][n], 0, 0, 0);
        acc4[m][n] = __builtin_amdgcn_mfma_f32_16x16x32_bf16(
            a[m], b2[n], acc4[m][n], 0, 0, 0);
      }
  };

  stage(0, 0); stage(1, 1);   // 6 loads in flight (2-ahead)
  for (int s = 0; s < 30; ++s) {
    WAITV(3);                          // own G(s) landed
    __builtin_amdgcn_s_barrier();
    __builtin_amdgcn_sched_barrier(0);
    stage((s + 2) % 3, s + 2);         // overwrites buf(s-1): reads done
    compute(s % 3);
  }
  WAITV(3);
  __builtin_amdgcn_s_barrier();
  __builtin_amdgcn_sched_barrier(0);
  compute(30 % 3);
  WAITV(0);
  __builtin_amdgcn_s_barrier();
  __builtin_amdgcn_sched_barrier(0);
  compute(31 % 3);

  const int or0 = bi * 64 + wr * 32, oc0 = bj * 64 + wc * 32;
#pragma unroll
  for (int m = 0; m < 2; ++m)
#pragma unroll
    for (int n = 0; n < 2; ++n) {
      const int row0 = or0 + m * 16 + (lane >> 4) * 4;
      const int col = oc0 + n * 16 + (lane & 15);
#pragma unroll
      for (int r = 0; r < 4; ++r) {
        const size_t idx = (size_t)(row0 + r) * D + col;
        const u16 x3v = f2bf(-acc3[m][n][r]);
        const u16 x4v = f2bf(acc4[m][n][r]);
        p.X3[mz][idx] = x3v;
        p.X4[mz][idx] = x4v;
        const float d = (row0 + r == col) ? 1.f : 0.f;
        const float xf = bf2f(p.X[mz][idx]);
        const float x2f = bf2f(p.X2[mz][idx]);
        const float x3f = bf2f(x3v), x4f = bf2f(x4v);
        p.q0[mz][idx] = d + xf + x2f * 0.5f + x3f * (1.f / 6.f);
        p.q1t[mz][idx] =
            f2bf(d * (1.f / 24.f) - xf * (1.f / 120.f) + x2f * (1.f / 720.f) -
                 x3f * (1.f / 5040.f) + x4f * (1.f / 40320.f));
      }
    }
}

// ---------------------------------------------------------------------------
// main GEMM (r10, unchanged): out[r][c] = (f(Xn,W) + bias[c])^2 * gate[c]
// 256x256 tile, BK=32, 8 waves (2x4), 4 LDS bufs (128 KiB), 3-ahead
// prefetch, counted vmcnt(8) before raw s_barrier (no full drains).
__global__ __launch_bounds__(512, 1) void main_gemm_kernel(
    const u16* __restrict__ Xn, const u16* __restrict__ Wm,
    const float* __restrict__ bias, const float* __restrict__ gate,
    float* __restrict__ out) {
  const int tid = threadIdx.x;
  const int wid = tid >> 6, lane = tid & 63;
  const int wr = wid >> 2, wc = wid & 3;   // 2 x 4 waves
  __shared__ u16 lds[4 * 16384];           // 4 bufs x (A 16KB + B 16KB)
  f32x4 acc[8][4];
#pragma unroll
  for (int m = 0; m < 8; ++m)
#pragma unroll
    for (int n = 0; n < 4; ++n) acc[m][n] = f32x4{0.f, 0.f, 0.f, 0.f};

  const int bi = blockIdx.x, bj = blockIdx.y;   // 128 x 4
  const int r_ = tid >> 2;   // 0..127
  const int c_ = tid & 3;

  auto stage = [&](int s) {
    char* base = (char*)lds + (s & 3) * 32768;
#pragma unroll
    for (int pp = 0; pp < 2; ++pp) {
      const int row = pp * 128 + r_;
      const int csrc = c_ ^ ((row >> 1) & 3);  // inverse swizzle on source
      g2l16(Xn + (size_t)(bi * 256 + row) * D + s * 32 + csrc * 8,
            base + pp * 8192 + tid * 16);
      g2l16(Wm + (size_t)(bj * 256 + row) * D + s * 32 + csrc * 8,
            base + 16384 + pp * 8192 + tid * 16);
    }
  };

  const int h = lane >> 4;  // k-chunk 0..3 within 32-wide step
  auto compute = [&](int s) {
    const char* base = (const char*)lds + (s & 3) * 32768;
    short8 a[8], b[4];
#pragma unroll
    for (int m = 0; m < 8; ++m) {
      const int row = wr * 128 + m * 16 + (lane & 15);
      const int off = row * 64 + ((h ^ ((row >> 1) & 3)) << 4);
      a[m] = *(const short8*)(base + off);
    }
#pragma unroll
    for (int n = 0; n < 4; ++n) {
      const int row = wc * 64 + n * 16 + (lane & 15);
      const int off = 16384 + row * 64 + ((h ^ ((row >> 1) & 3)) << 4);
      b[n] = *(const short8*)(base + off);
    }
    __builtin_amdgcn_s_setprio(1);
#pragma unroll
    for (int m = 0; m < 8; ++m)
#pragma unroll
      for (int n = 0; n < 4; ++n)
        acc[m][n] = __builtin_amdgcn_mfma_f32_16x16x32_bf16(a[m], b[n],
                                                            acc[m][n], 0, 0, 0);
    __builtin_amdgcn_s_setprio(0);
  };

  stage(0); stage(1); stage(2);   // 12 loads in flight
  for (int s = 0; s < 29; ++s) {
    WAITV(8);
    __builtin_amdgcn_s_barrier();
    __builtin_amdgcn_sched_barrier(0);
    stage(s + 3);
    compute(s);
  }
  WAITV(8);
  __builtin_amdgcn_s_barrier();
  __builtin_amdgcn_sched_barrier(0);
  compute(29);
  WAITV(4);
  __builtin_amdgcn_s_barrier();
  __builtin_amdgcn_sched_barrier(0);
  compute(30);
  WAITV(0);
  __builtin_amdgcn_s_barrier();
  __builtin_amdgcn_sched_barrier(0);
  compute(31);

  const int or0 = bi * 256 + wr * 128, oc0 = bj * 256 + wc * 64;
#pragma unroll
  for (int m = 0; m < 8; ++m)
#pragma unroll
    for (int n = 0; n < 4; ++n) {
      const int col = oc0 + n * 16 + (lane & 15);
      const float bc = bias[col], gc = gate[col];
#pragma unroll
      for (int r = 0; r < 4; ++r) {
        const int row = or0 + m * 16 + (lane >> 4) * 4 + r;
        const float t = acc[m][n][r] + bc;
        out[(size_t)row * D + col] = t * t * gc;
      }
    }
}

// ---------------------------------------------------------------------------
extern "C" void kernel_launch(void* const* d_in, const int* in_sizes, int n_in,
                              void* d_out, int out_size, void* d_ws,
                              size_t ws_size, hipStream_t stream) {
  (void)in_sizes; (void)n_in; (void)out_size; (void)ws_size;
  const float* inp = (const float*)d_in[0];
  const float* Mr = (const float*)d_in[1];
  const float* Mi = (const float*)d_in[2];
  const float* bias = (const float*)d_in[3];
  const float* qg = (const float*)d_in[4];
  float* out = (float*)d_out;
  float* gate_out = out + (size_t)32768 * 1024;

  char* ws = (char*)d_ws;
  u16* Xn = (u16*)ws;  // 64 MB
  // per-matrix region (16 MB): 6 bf16 slots (2 MB) + q0 (4 MB f32).
  // lifetimes: s0 X->E3, s1 X2->Et->E3t, s2 X3->E1, s3 X4->E2,
  //            s4 q1t->E1t, s5 E2t
  auto slot = [&](int m, int s) -> u16* {
    return (u16*)(ws + 67108864 + (size_t)m * 16777216 + (size_t)s * 2097152);
  };
  auto q0p = [&](int m) -> float* {
    return (float*)(ws + 67108864 + (size_t)m * 16777216 + 12582912);
  };
  u16* W = (u16*)(ws + 100663296);  // 96 MB: 2 MB

  // normalize rows: 8 launches x 4096 rows (512 blocks of 8 rows each)
  const int CH = 4096, NB = 512;
  int row0 = 0;

  // L1: skew
  {
    SkewParams sp{Mr, Mi, slot(0, 0), slot(1, 0), inp, Xn, row0};
    skew_norm_kernel<<<512 + NB, 256, 0, stream>>>(sp);
    row0 += CH;
  }
  GNParams gp{};
  gp.x = inp; gp.Xn = Xn;
  // L2: X2 = -f(X,X) -> s1
  for (int m = 0; m < 2; ++m)
    gp.jobs[m] = CJob{slot(m, 0), slot(m, 0), nullptr, slot(m, 1), nullptr,
                      -1.f};
  gp.njobs = 512; gp.row0 = row0;
  gemm_norm_kernel<<<512 + NB, 256, 0, stream>>>(gp);
  row0 += CH;
  // L3: fused X3/X4 + buildq + gate
  {
    X34Params xp{};
    for (int m = 0; m < 2; ++m) {
      xp.X[m] = slot(m, 0); xp.X2[m] = slot(m, 1);
      xp.X3[m] = slot(m, 2); xp.X4[m] = slot(m, 3);
      xp.q1t[m] = slot(m, 4); xp.q0[m] = q0p(m);
    }
    xp.qg = qg; xp.gate_out = gate_out;
    xp.x = inp; xp.Xn = Xn; xp.row0 = row0;
    x34q_norm_kernel<<<513 + NB, 256, 0, stream>>>(xp);
    row0 += CH;
  }
  // L4: E = f(X4, q1t) + q0 -> s0, dual Et -> s1
  for (int m = 0; m < 2; ++m)
    gp.jobs[m] = CJob{slot(m, 3), slot(m, 4), q0p(m), slot(m, 0), slot(m, 1),
                      1.f};
  gp.njobs = 512; gp.row0 = row0;
  gemm_norm_kernel<<<512 + NB, 256, 0, stream>>>(gp);
  row0 += CH;
  // L5: sq1: E1 = f(E,Et) -> s2, dual E1t -> s4
  for (int m = 0; m < 2; ++m)
    gp.jobs[m] = CJob{slot(m, 0), slot(m, 1), nullptr, slot(m, 2), slot(m, 4),
                      1.f};
  gp.row0 = row0;
  gemm_norm_kernel<<<512 + NB, 256, 0, stream>>>(gp);
  row0 += CH;
  // L6: sq2: E2 = f(E1,E1t) -> s3, dual E2t -> s5
  for (int m = 0; m < 2; ++m)
    gp.jobs[m] = CJob{slot(m, 2), slot(m, 4), nullptr, slot(m, 3), slot(m, 5),
                      1.f};
  gp.row0 = row0;
  gemm_norm_kernel<<<512 + NB, 256, 0, stream>>>(gp);
  row0 += CH;
  // L7: sq3: E3 = f(E2,E2t) -> s0, dual E3t -> s1
  for (int m = 0; m < 2; ++m)
    gp.jobs[m] = CJob{slot(m, 3), slot(m, 5), nullptr, slot(m, 0), slot(m, 1),
                      1.f};
  gp.row0 = row0;
  gemm_norm_kernel<<<512 + NB, 256, 0, stream>>>(gp);
  row0 += CH;
  // L8: W = U^T = f(E3t_B, E3_A)
  gp.jobs[0] = CJob{slot(1, 1), slot(0, 0), nullptr, W, nullptr, 1.f};
  gp.njobs = 256; gp.row0 = row0;
  gemm_norm_kernel<<<256 + NB, 256, 0, stream>>>(gp);

  main_gemm_kernel<<<dim3(128, 4), 512, 0, stream>>>(Xn, W, bias, gate_out,
                                                     out);
}